// Round 1
// baseline (4132.599 us; speedup 1.0000x reference)
//
#include <hip/hip_runtime.h>
#include <math.h>

// ---------------------------------------------------------------------------
// Generic 3x3 SAME conv + BN + ReLU (+ optional fused 2x2 maxpool).
// Block: 256 threads = (8x8 pixel patches) x (4 cout groups).
// Each thread computes a 2x2 conv patch for 4 consecutive couts.
// Input tile (18x18 halo, LDS row stride 20) + weights (co-major, float4
// readable) staged per CICHUNK of input channels.
// ---------------------------------------------------------------------------
template<int CIN, int COUT, int HI, int WI, int POOL, int CICHUNK>
__global__ __launch_bounds__(256) void conv_bn_relu(
    const float* __restrict__ in, const float* __restrict__ wgt,
    const float* __restrict__ cb, const float* __restrict__ sc,
    const float* __restrict__ tb, float* __restrict__ out)
{
    constexpr int HO = HI / POOL, WO = WI / POOL;
    constexpr int TILES_X = WI / 16;

    const int tid = threadIdx.x;
    const int px = tid & 7;
    const int py = (tid >> 3) & 7;
    const int cg = tid >> 6;              // 0..3 (wave-uniform)
    const int tile = blockIdx.x;
    const int ty = tile / TILES_X, tx = tile % TILES_X;
    const int y0 = ty * 16, x0 = tx * 16; // conv-space tile origin
    const int b  = blockIdx.z;
    const int coBase = blockIdx.y * 16;

    __shared__ float s_in[CICHUNK][18 * 20];          // rows stride 20
    __shared__ __align__(16) float s_w[CICHUNK * 9][16]; // [ci*9+k][co_local]

    float acc[4][2][2];
#pragma unroll
    for (int a = 0; a < 4; a++)
#pragma unroll
        for (int i = 0; i < 2; i++)
#pragma unroll
            for (int j = 0; j < 2; j++) acc[a][i][j] = 0.f;

    for (int ci0 = 0; ci0 < CIN; ci0 += CICHUNK) {
        // ---- stage input tile (18x18 per ci), zero-padded at borders ----
        for (int idx = tid; idx < CICHUNK * 324; idx += 256) {
            int ci = idx / 324, rem = idx % 324;
            int r = rem / 18, c = rem % 18;
            int gy = y0 + r - 1, gx = x0 + c - 1;
            float v = 0.f;
            if (gy >= 0 && gy < HI && gx >= 0 && gx < WI)
                v = in[(((size_t)b * CIN + (ci0 + ci)) * HI + gy) * WI + gx];
            s_in[ci][r * 20 + c] = v;
        }
        // ---- stage weights, co fastest (conflict-free LDS writes) ----
        for (int idx = tid; idx < 16 * CICHUNK * 9; idx += 256) {
            int co = idx & 15;
            int rr = idx >> 4;            // ci*9 + k
            int ci = rr / 9, k = rr % 9;
            s_w[rr][co] = wgt[(((size_t)(coBase + co) * CIN) + ci0 + ci) * 9 + k];
        }
        __syncthreads();

        for (int ci = 0; ci < CICHUNK; ci++) {
            // 4x4 input patch for this thread's 2x2 conv pixels
            float p[4][4];
#pragma unroll
            for (int r = 0; r < 4; r++)
#pragma unroll
                for (int c = 0; c < 4; c++)
                    p[r][c] = s_in[ci][(2 * py + r) * 20 + 2 * px + c];

#pragma unroll
            for (int k = 0; k < 9; k++) {
                const float4 w4 = *reinterpret_cast<const float4*>(&s_w[ci * 9 + k][cg * 4]);
                const float wv[4] = {w4.x, w4.y, w4.z, w4.w};
                const int ky = k / 3, kx = k % 3;
#pragma unroll
                for (int co = 0; co < 4; co++)
#pragma unroll
                    for (int dy = 0; dy < 2; dy++)
#pragma unroll
                        for (int dx = 0; dx < 2; dx++)
                            acc[co][dy][dx] += p[dy + ky][dx + kx] * wv[co];
            }
        }
        __syncthreads();
    }

    // ---- epilogue: BN + ReLU (+ pool2) ----
#pragma unroll
    for (int co = 0; co < 4; co++) {
        const int coG = coBase + cg * 4 + co;
        const float bb = cb[coG], ss = sc[coG], tt = tb[coG];
        if (POOL == 1) {
#pragma unroll
            for (int dy = 0; dy < 2; dy++)
#pragma unroll
                for (int dx = 0; dx < 2; dx++) {
                    float v = fmaxf((acc[co][dy][dx] + bb) * ss + tt, 0.f);
                    int oy = y0 + 2 * py + dy, ox = x0 + 2 * px + dx;
                    out[(((size_t)b * COUT + coG) * HO + oy) * WO + ox] = v;
                }
        } else {
            float m = -INFINITY;
#pragma unroll
            for (int dy = 0; dy < 2; dy++)
#pragma unroll
                for (int dx = 0; dx < 2; dx++)
                    m = fmaxf(m, (acc[co][dy][dx] + bb) * ss + tt);
            m = fmaxf(m, 0.f);
            int oy = (y0 >> 1) + py, ox = (x0 >> 1) + px;
            out[(((size_t)b * COUT + coG) * HO + oy) * WO + ox] = m;
        }
    }
}

// acc layout fix for the thread's 4 couts: index [co] above maps to
// coBase + cg*4 + co (cg wave-uniform) — weights were read from s_w[..][cg*4+co].

// ---------------------------------------------------------------------------
// 6x6/6 VALID maxpool: (Bc,128,16,16) -> (Bc,128,2,2) flattened features
// ---------------------------------------------------------------------------
__global__ void pool6_kernel(const float* __restrict__ in, float* __restrict__ out, int nb)
{
    int t = blockIdx.x * 256 + threadIdx.x;
    if (t >= nb * 128 * 4) return;
    int ox = t & 1, oy = (t >> 1) & 1, c = (t >> 2) & 127, b = t >> 9;
    const float* p = in + (((size_t)(b * 128 + c) * 16 + oy * 6) * 16 + ox * 6);
    float m = -INFINITY;
#pragma unroll
    for (int r = 0; r < 6; r++)
#pragma unroll
        for (int cc = 0; cc < 6; cc++) m = fmaxf(m, p[r * 16 + cc]);
    out[t] = m;
}

// ---------------------------------------------------------------------------
// FC1: (64,512) @ fcw.T (512,1024) + fcb, ReLU
// ---------------------------------------------------------------------------
__global__ void fc1_kernel(const float* __restrict__ flat, const float* __restrict__ fcw,
                           const float* __restrict__ fcb, float* __restrict__ out1)
{
    int b = blockIdx.y;
    int j = blockIdx.x * 256 + threadIdx.x;
    float s = fcb[j];
    const float* f = flat + (size_t)b * 512;
    const float* w = fcw + (size_t)j * 512;
    for (int k = 0; k < 512; k++) s += f[k] * w[k];
    out1[(size_t)b * 1024 + j] = fmaxf(s, 0.f);
}

// ---------------------------------------------------------------------------
// FC2: (64,1024) @ f1w.T (1024,8) + f1b -> H4PT
// ---------------------------------------------------------------------------
__global__ void fc2_kernel(const float* __restrict__ out1, const float* __restrict__ f1w,
                           const float* __restrict__ f1b, float* __restrict__ h4pt)
{
    int t = threadIdx.x;            // 512 = 64 b x 8 i
    int b = t >> 3, i = t & 7;
    float s = f1b[i];
    const float* o = out1 + (size_t)b * 1024;
    const float* w = f1w + (size_t)i * 1024;
    for (int k = 0; k < 1024; k++) s += o[k] * w[k];
    h4pt[b * 8 + i] = s;
}

// ---------------------------------------------------------------------------
// DLT (8x8 solve, fp64, partial pivoting) + 3x3 inverse -> Hinv (fp64)
// ---------------------------------------------------------------------------
__global__ void dlt_kernel(const float* __restrict__ h4pt, const float* __restrict__ corner,
                           double* __restrict__ hinv)
{
    int b = threadIdx.x;
    if (b >= 64) return;
    double U[4], V[4], Ud[4], Vd[4];
    for (int j = 0; j < 4; j++) {
        U[j] = (double)corner[b * 8 + 2 * j];
        V[j] = (double)corner[b * 8 + 2 * j + 1];
        Ud[j] = U[j] + (double)h4pt[b * 8 + 2 * j];
        Vd[j] = V[j] + (double)h4pt[b * 8 + 2 * j + 1];
    }
    double A[8][9];
    for (int j = 0; j < 4; j++) {
        double* r0 = A[2 * j];
        double* r1 = A[2 * j + 1];
        r0[0] = 0;    r0[1] = 0;    r0[2] = 0;
        r0[3] = -U[j]; r0[4] = V[j]; r0[5] = -1;
        r0[6] = Vd[j] * U[j]; r0[7] = Vd[j] * V[j]; r0[8] = -Vd[j];
        r1[0] = U[j]; r1[1] = V[j]; r1[2] = 1;
        r1[3] = 0;    r1[4] = 0;    r1[5] = 0;
        r1[6] = -Ud[j] * U[j]; r1[7] = -Ud[j] * V[j]; r1[8] = Ud[j];
    }
    // Gaussian elimination with partial pivoting on augmented [A|b]
    for (int col = 0; col < 8; col++) {
        int piv = col; double mx = fabs(A[col][col]);
        for (int r = col + 1; r < 8; r++) {
            double v = fabs(A[r][col]);
            if (v > mx) { mx = v; piv = r; }
        }
        if (piv != col)
            for (int c = col; c < 9; c++) { double tmp = A[col][c]; A[col][c] = A[piv][c]; A[piv][c] = tmp; }
        double inv = 1.0 / A[col][col];
        for (int r = col + 1; r < 8; r++) {
            double f = A[r][col] * inv;
            for (int c = col; c < 9; c++) A[r][c] -= f * A[col][c];
        }
    }
    double h[9];
    for (int r = 7; r >= 0; r--) {
        double s = A[r][8];
        for (int c = r + 1; c < 8; c++) s -= A[r][c] * h[c];
        h[r] = s / A[r][r];
    }
    h[8] = 1.0;
    // 3x3 inverse via adjugate
    double a = h[0], bb = h[1], c = h[2], d = h[3], e = h[4], f = h[5], g = h[6], hh = h[7], i = h[8];
    double C00 = e * i - f * hh, C01 = c * hh - bb * i, C02 = bb * f - c * e;
    double C10 = f * g - d * i,  C11 = a * i - c * g,   C12 = c * d - a * f;
    double C20 = d * hh - e * g, C21 = bb * g - a * hh, C22 = a * e - bb * d;
    double det = a * C00 + bb * C10 + c * C20;
    double idet = 1.0 / det;
    double* o = hinv + b * 9;
    o[0] = C00 * idet; o[1] = C01 * idet; o[2] = C02 * idet;
    o[3] = C10 * idet; o[4] = C11 * idet; o[5] = C12 * idet;
    o[6] = C20 * idet; o[7] = C21 * idet; o[8] = C22 * idet;
}

// ---------------------------------------------------------------------------
// Perspective warp + bilinear sample (coords fp64, gather fp32)
// ---------------------------------------------------------------------------
__global__ void warp_kernel(const float* __restrict__ img, const double* __restrict__ hinv,
                            float* __restrict__ out)
{
    int b = blockIdx.y;
    int pix = blockIdx.x * 256 + threadIdx.x;   // 16384 per image
    int y = pix >> 7, x = pix & 127;
    const double* h = hinv + b * 9;
    double X = (double)x, Y = (double)y;
    double p0 = h[0] * X + h[1] * Y + h[2];
    double p1 = h[3] * X + h[4] * Y + h[5];
    double p2 = h[6] * X + h[7] * Y + h[8];
    double xs = p0 / p2, ys = p1 / p2;
    double x0d = floor(xs), y0d = floor(ys);
    double wx = xs - x0d, wy = ys - y0d;
    int x0 = (int)x0d, y0 = (int)y0d;
    const float* im = img + (size_t)b * 240 * 320;

    auto gat = [&](int yi, int xi) -> double {
        bool valid = (xi >= 0) & (xi < 320) & (yi >= 0) & (yi < 240);
        int yc = yi < 0 ? 0 : (yi > 239 ? 239 : yi);
        int xc = xi < 0 ? 0 : (xi > 319 ? 319 : xi);
        double v = (double)im[yc * 320 + xc];
        return valid ? v : 0.0;
    };
    double v00 = gat(y0, x0),     v01 = gat(y0, x0 + 1);
    double v10 = gat(y0 + 1, x0), v11 = gat(y0 + 1, x0 + 1);
    double r = v00 * (1 - wx) * (1 - wy) + v01 * wx * (1 - wy)
             + v10 * (1 - wx) * wy       + v11 * wx * wy;
    out[((size_t)b << 14) + pix] = (float)r;
}

// ---------------------------------------------------------------------------
// launch
// ---------------------------------------------------------------------------
extern "C" void kernel_launch(void* const* d_in, const int* in_sizes, int n_in,
                              void* d_out, int out_size, void* d_ws, size_t ws_size,
                              hipStream_t stream)
{
    const float* TI1     = (const float*)d_in[1];   // (64,2,128,128)
    const float* TImgA   = (const float*)d_in[2];   // (64,240,320)
    const float* TCorner = (const float*)d_in[3];   // (64,8)
    const float* w[8], *cbp[8], *sp[8], *tp[8];
    for (int i = 0; i < 8; i++) {
        w[i]   = (const float*)d_in[4 + 4 * i];
        cbp[i] = (const float*)d_in[5 + 4 * i];
        sp[i]  = (const float*)d_in[6 + 4 * i];
        tp[i]  = (const float*)d_in[7 + 4 * i];
    }
    const float* fcw = (const float*)d_in[36];
    const float* fcb = (const float*)d_in[37];
    const float* f1w = (const float*)d_in[38];
    const float* f1b = (const float*)d_in[39];

    float* ws   = (float*)d_ws;
    float* bufA = ws;                       // 16*64*128*128 = 16,777,216 floats
    float* bufB = bufA + 16777216;          // 16*64*64*64   =  4,194,304 floats
    float* feat = bufB + 4194304;           // 64*512
    float* fc1o = feat + 32768;             // 64*1024
    float* h4pt = fc1o + 65536;             // 64*8
    double* hinv = (double*)(h4pt + 512);   // 64*9 doubles (8B aligned)
    float* outp = (float*)d_out;

    // conv stack in 4 batch chunks of 16 images (~85 MB workspace)
    for (int ch = 0; ch < 4; ch++) {
        const float* in1 = TI1 + (size_t)ch * 16 * 2 * 128 * 128;
        conv_bn_relu<2, 64, 128, 128, 1, 2><<<dim3(64, 4, 16), 256, 0, stream>>>(
            in1, w[0], cbp[0], sp[0], tp[0], bufA);
        conv_bn_relu<64, 64, 128, 128, 2, 8><<<dim3(64, 4, 16), 256, 0, stream>>>(
            bufA, w[1], cbp[1], sp[1], tp[1], bufB);
        conv_bn_relu<64, 64, 64, 64, 1, 8><<<dim3(16, 4, 16), 256, 0, stream>>>(
            bufB, w[2], cbp[2], sp[2], tp[2], bufA);
        conv_bn_relu<64, 64, 64, 64, 2, 8><<<dim3(16, 4, 16), 256, 0, stream>>>(
            bufA, w[3], cbp[3], sp[3], tp[3], bufB);
        conv_bn_relu<64, 128, 32, 32, 1, 8><<<dim3(4, 8, 16), 256, 0, stream>>>(
            bufB, w[4], cbp[4], sp[4], tp[4], bufA);
        conv_bn_relu<128, 128, 32, 32, 2, 8><<<dim3(4, 8, 16), 256, 0, stream>>>(
            bufA, w[5], cbp[5], sp[5], tp[5], bufB);
        conv_bn_relu<128, 128, 16, 16, 1, 8><<<dim3(1, 8, 16), 256, 0, stream>>>(
            bufB, w[6], cbp[6], sp[6], tp[6], bufA);
        conv_bn_relu<128, 128, 16, 16, 1, 8><<<dim3(1, 8, 16), 256, 0, stream>>>(
            bufA, w[7], cbp[7], sp[7], tp[7], bufB);
        pool6_kernel<<<32, 256, 0, stream>>>(bufB, feat + (size_t)ch * 16 * 512, 16);
    }

    fc1_kernel<<<dim3(4, 64), 256, 0, stream>>>(feat, fcw, fcb, fc1o);
    fc2_kernel<<<1, 512, 0, stream>>>(fc1o, f1w, f1b, h4pt);
    dlt_kernel<<<1, 64, 0, stream>>>(h4pt, TCorner, hinv);
    warp_kernel<<<dim3(64, 64), 256, 0, stream>>>(TImgA, hinv, outp);
}

// Round 2
// 929.622 us; speedup vs baseline: 4.4455x; 4.4455x over previous
//
#include <hip/hip_runtime.h>
#include <math.h>

typedef __attribute__((ext_vector_type(4))) float f32x4;
typedef __attribute__((ext_vector_type(8))) short sh8;

__device__ __forceinline__ float bf2f(unsigned short u){
    union { unsigned int i; float f; } v; v.i = ((unsigned)u) << 16; return v.f;
}
__device__ __forceinline__ unsigned short f2bf(float f){
    union { float f; unsigned int i; } v; v.f = f;
    unsigned int x = v.i;
    x += 0x7fff + ((x >> 16) & 1);   // RNE; inputs finite
    return (unsigned short)(x >> 16);
}

// ---------------------------------------------------------------------------
// Weight transform: w [COUT][CIN][3][3] fp32 -> wT{hi,lo} [tap][COUT][CIN] bf16
// ---------------------------------------------------------------------------
__global__ void wtrans(const float* __restrict__ w, unsigned short* __restrict__ whi,
                       unsigned short* __restrict__ wlo, int COUT, int CIN)
{
    int e = blockIdx.x * 256 + threadIdx.x;
    int n = COUT * CIN * 9;
    if (e >= n) return;
    int tap = e % 9, rest = e / 9;
    int ci = rest % CIN, co = rest / CIN;
    float v = w[e];
    unsigned short hi = f2bf(v);
    unsigned short lo = f2bf(v - bf2f(hi));
    int dst = (tap * COUT + co) * CIN + ci;
    whi[dst] = hi; wlo[dst] = lo;
}

// ---------------------------------------------------------------------------
// conv1: Cin=2 fp32 direct conv + BN + ReLU -> NHWC bf16 out
// block 256 = 8 cout-groups x 32 spatial slots; thread: 2x4 pixels x 8 couts
// ---------------------------------------------------------------------------
__global__ __launch_bounds__(256) void conv1_kernel(
    const float* __restrict__ in, const float* __restrict__ w,
    const float* __restrict__ cb, const float* __restrict__ sc,
    const float* __restrict__ tb, unsigned short* __restrict__ out)
{
    __shared__ float s_w[18 * 64];        // [ci*9+k][co]
    __shared__ float s_in[2][18 * 20];    // halo 18x18, stride 20

    const int tid = threadIdx.x;
    const int b = blockIdx.y;
    const int tile = blockIdx.x;          // 64 tiles of 16x16
    const int ty = tile >> 3, tx = tile & 7;
    const int y0 = ty * 16, x0 = tx * 16;

    for (int idx = tid; idx < 1152; idx += 256) {
        int co = idx & 63, kk2 = idx >> 6;
        s_w[kk2 * 64 + co] = w[co * 18 + kk2];
    }
    for (int idx = tid; idx < 2 * 324; idx += 256) {
        int ci = idx / 324, rem = idx % 324;
        int r = rem / 18, c = rem % 18;
        int gy = y0 + r - 1, gx = x0 + c - 1;
        float v = 0.f;
        if (gy >= 0 && gy < 128 && gx >= 0 && gx < 128)
            v = in[((size_t)(b * 2 + ci) * 128 + gy) * 128 + gx];
        s_in[ci][r * 20 + c] = v;
    }
    __syncthreads();

    const int cog = tid >> 5;             // 8 couts: cog*8..+7
    const int slot = tid & 31;
    const int sy = slot >> 2, sx = slot & 3;  // rows 2sy..2sy+1, cols 4sx..4sx+3

    float p[2][4][6];
#pragma unroll
    for (int ci = 0; ci < 2; ci++)
#pragma unroll
        for (int r = 0; r < 4; r++)
#pragma unroll
            for (int c = 0; c < 6; c++)
                p[ci][r][c] = s_in[ci][(2 * sy + r) * 20 + 4 * sx + c];

    float acc[2][4][8];
#pragma unroll
    for (int r = 0; r < 2; r++)
#pragma unroll
        for (int c = 0; c < 4; c++)
#pragma unroll
            for (int o = 0; o < 8; o++) acc[r][c][o] = 0.f;

#pragma unroll
    for (int kk2 = 0; kk2 < 18; kk2++) {
        const int ci = kk2 / 9, k = kk2 % 9;
        const int ky = k / 3, kx = k % 3;
        float wv[8];
#pragma unroll
        for (int q = 0; q < 2; q++) {
            f32x4 w4 = *(const f32x4*)(&s_w[kk2 * 64 + cog * 8 + q * 4]);
#pragma unroll
            for (int z = 0; z < 4; z++) wv[q * 4 + z] = w4[z];
        }
#pragma unroll
        for (int r = 0; r < 2; r++)
#pragma unroll
            for (int c = 0; c < 4; c++) {
                float pv = p[ci][r + ky][c + kx];
#pragma unroll
                for (int o = 0; o < 8; o++) acc[r][c][o] += pv * wv[o];
            }
    }

    float bb[8], ss[8], tt[8];
#pragma unroll
    for (int o = 0; o < 8; o++) { bb[o] = cb[cog*8+o]; ss[o] = sc[cog*8+o]; tt[o] = tb[cog*8+o]; }
#pragma unroll
    for (int r = 0; r < 2; r++)
#pragma unroll
        for (int c = 0; c < 4; c++) {
            unsigned short ov[8];
#pragma unroll
            for (int o = 0; o < 8; o++)
                ov[o] = f2bf(fmaxf((acc[r][c][o] + bb[o]) * ss[o] + tt[o], 0.f));
            int py = y0 + 2 * sy + r, px = x0 + 4 * sx + c;
            *(sh8*)(out + ((size_t)(b * 128 + py) * 128 + px) * 64 + cog * 8) = *(sh8*)ov;
        }
}

// ---------------------------------------------------------------------------
// MFMA implicit-GEMM conv3x3 SAME + BN + ReLU (+ fused 2x2 maxpool)
// in/out NHWC bf16; weights [tap][COUT][CIN] bf16 hi/lo (2-term split)
// block 256 = 4 waves (2 pixgrp x 2 coutgrp); tile 128 pixels (TH x TW) x 64 couts
// ---------------------------------------------------------------------------
template<int CIN, int COUT, int HI, int WI, int POOL, int TW>
__global__ __launch_bounds__(256, 2) void conv_mfma(
    const unsigned short* __restrict__ in,
    const unsigned short* __restrict__ whi, const unsigned short* __restrict__ wlo,
    const float* __restrict__ cb, const float* __restrict__ sc,
    const float* __restrict__ tb, unsigned short* __restrict__ out)
{
    constexpr int TH = 128 / TW;
    constexpr int HALW = TW + 2, HALH = TH + 2;
    constexpr int NPIX = HALW * HALH;
    constexpr int CHUNKS = CIN / 64;
    constexpr int TILESX = WI / TW;
    constexpr int HO = HI / POOL, WO = WI / POOL;
    constexpr int ST = 72;               // ushorts per pixel row (144B: 128 data + 16 pad)

    __shared__ __align__(16) unsigned short lds[NPIX * ST];

    const int tid = threadIdx.x;
    const int lane = tid & 63;
    const int i = lane & 15, j = lane >> 4;
    const int wv_ = tid >> 6;
    const int pg = wv_ & 1, cg = wv_ >> 1;
    const int tile = blockIdx.x;
    const int ty = tile / TILESX, tx = tile % TILESX;
    const int y0 = ty * TH, x0 = tx * TW;
    const int cogrp = blockIdx.y;
    const int b = blockIdx.z;

    f32x4 acc[4][2];
#pragma unroll
    for (int pf = 0; pf < 4; pf++)
#pragma unroll
        for (int cf = 0; cf < 2; cf++) acc[pf][cf] = (f32x4){0.f, 0.f, 0.f, 0.f};

    for (int c = 0; c < CHUNKS; c++) {
        if (c) __syncthreads();
        // ---- stage halo tile: NPIX pixels x 64 cin (128B each), zero-padded ----
        for (int u = tid; u < NPIX * 8; u += 256) {
            int hp = u >> 3, c16 = u & 7;
            int hy = hp / HALW, hx = hp % HALW;
            int gy = y0 + hy - 1, gx = x0 + hx - 1;
            sh8 v = (sh8){0,0,0,0,0,0,0,0};
            if (gy >= 0 && gy < HI && gx >= 0 && gx < WI)
                v = *(const sh8*)(in + ((size_t)(b * HI + gy) * WI + gx) * CIN + c * 64 + c16 * 8);
            *(sh8*)(&lds[hp * ST + c16 * 8]) = v;
        }
        __syncthreads();

#pragma unroll
        for (int tap = 0; tap < 9; tap++) {
            const int ky = tap / 3, kx = tap % 3;
#pragma unroll
            for (int kk = 0; kk < 2; kk++) {
                sh8 bh[2], bl[2];
#pragma unroll
                for (int cf = 0; cf < 2; cf++) {
                    int co = cogrp * 64 + cg * 32 + cf * 16 + i;
                    size_t wo = ((size_t)(tap * COUT + co)) * CIN + c * 64 + kk * 32 + j * 8;
                    bh[cf] = *(const sh8*)(whi + wo);
                    bl[cf] = *(const sh8*)(wlo + wo);
                }
                sh8 a[4];
#pragma unroll
                for (int pf = 0; pf < 4; pf++) {
                    int nf = pg * 4 + pf;
                    int hy2, hx2;
                    if (TW == 32) { hy2 = (nf >> 1) + ky; hx2 = (nf & 1) * 16 + i + kx; }
                    else          { hy2 = nf + ky;        hx2 = i + kx; }
                    a[pf] = *(const sh8*)(&lds[(hy2 * HALW + hx2) * ST + kk * 32 + j * 8]);
                }
#pragma unroll
                for (int pf = 0; pf < 4; pf++)
#pragma unroll
                    for (int cf = 0; cf < 2; cf++) {
                        acc[pf][cf] = __builtin_amdgcn_mfma_f32_16x16x32_bf16(a[pf], bh[cf], acc[pf][cf], 0, 0, 0);
                        acc[pf][cf] = __builtin_amdgcn_mfma_f32_16x16x32_bf16(a[pf], bl[cf], acc[pf][cf], 0, 0, 0);
                    }
            }
        }
    }

    // ---- epilogue: BN + ReLU (+pool) ; D: col(i)=cout, row(j*4+r)=pixel ----
    const int cbase = cogrp * 64 + cg * 32;
#pragma unroll
    for (int cf = 0; cf < 2; cf++) {
        const int co = cbase + cf * 16 + i;
        const float b3 = cb[co], s3 = sc[co], t3 = tb[co];
        if (POOL == 1) {
#pragma unroll
            for (int pf = 0; pf < 4; pf++) {
                const int nf = pg * 4 + pf;
                int py, pxb;
                if (TW == 32) { py = nf >> 1; pxb = (nf & 1) * 16; }
                else          { py = nf;      pxb = 0; }
#pragma unroll
                for (int r = 0; r < 4; r++) {
                    float v = fmaxf((acc[pf][cf][r] + b3) * s3 + t3, 0.f);
                    int px = pxb + j * 4 + r;
                    out[((size_t)(b * HO + y0 + py) * WO + x0 + px) * COUT + co] = f2bf(v);
                }
            }
        } else if constexpr (POOL == 2 && TW == 32) {
            // wave rows py = 2pg,2pg+1 -> pooled row pg; col pairs within lane (r)
#pragma unroll
            for (int half = 0; half < 2; half++) {
                const int pfA = half, pfB = 2 + half;
#pragma unroll
                for (int r2 = 0; r2 < 2; r2++) {
                    float vA0 = fmaxf((acc[pfA][cf][2*r2]   + b3) * s3 + t3, 0.f);
                    float vA1 = fmaxf((acc[pfA][cf][2*r2+1] + b3) * s3 + t3, 0.f);
                    float vB0 = fmaxf((acc[pfB][cf][2*r2]   + b3) * s3 + t3, 0.f);
                    float vB1 = fmaxf((acc[pfB][cf][2*r2+1] + b3) * s3 + t3, 0.f);
                    float v = fmaxf(fmaxf(vA0, vA1), fmaxf(vB0, vB1));
                    int pox = (x0 >> 1) + half * 8 + j * 2 + r2;
                    int poy = (y0 >> 1) + pg;
                    out[((size_t)(b * HO + poy) * WO + pox) * COUT + co] = f2bf(v);
                }
            }
        }
    }
}

// ---------------------------------------------------------------------------
// 6x6/6 maxpool on NHWC bf16 (64,16,16,128) -> feat fp32 [b][c*4+oy*2+ox]
// ---------------------------------------------------------------------------
__global__ void pool6_kernel(const unsigned short* __restrict__ in, float* __restrict__ out)
{
    int t = blockIdx.x * 256 + threadIdx.x;
    if (t >= 64 * 128 * 4) return;
    int ox = t & 1, oy = (t >> 1) & 1, c = (t >> 2) & 127, b = t >> 9;
    const unsigned short* p = in + ((size_t)(b * 16 + oy * 6) * 16 + ox * 6) * 128 + c;
    float m = -INFINITY;
#pragma unroll
    for (int r = 0; r < 6; r++)
#pragma unroll
        for (int cc = 0; cc < 6; cc++) m = fmaxf(m, bf2f(p[(r * 16 + cc) * 128]));
    out[(size_t)b * 512 + c * 4 + oy * 2 + ox] = m;
}

// ---------------------------------------------------------------------------
// FC1: (64,512) @ fcw.T + fcb, ReLU  (vectorized)
// ---------------------------------------------------------------------------
__global__ void fc1_kernel(const float* __restrict__ flat, const float* __restrict__ fcw,
                           const float* __restrict__ fcb, float* __restrict__ out1)
{
    int b = blockIdx.y;
    int jj = blockIdx.x * 256 + threadIdx.x;
    const f32x4* f = (const f32x4*)(flat + (size_t)b * 512);
    const f32x4* w = (const f32x4*)(fcw + (size_t)jj * 512);
    float s = fcb[jj];
    for (int k = 0; k < 128; k++) {
        f32x4 a = f[k], ww = w[k];
        s += a[0]*ww[0] + a[1]*ww[1] + a[2]*ww[2] + a[3]*ww[3];
    }
    out1[(size_t)b * 1024 + jj] = fmaxf(s, 0.f);
}

// ---------------------------------------------------------------------------
// FC2: (64,1024) @ f1w.T + f1b -> H4PT ; block per image, 8 out x 32 lanes
// ---------------------------------------------------------------------------
__global__ void fc2_kernel(const float* __restrict__ out1, const float* __restrict__ f1w,
                           const float* __restrict__ f1b, float* __restrict__ h4pt)
{
    int b = blockIdx.x;
    int o = threadIdx.x >> 5, s2 = threadIdx.x & 31;
    const float* pa = out1 + (size_t)b * 1024;
    const float* pw = f1w + (size_t)o * 1024;
    float s = 0.f;
    for (int k = s2; k < 1024; k += 32) s += pa[k] * pw[k];
#pragma unroll
    for (int m = 16; m; m >>= 1) s += __shfl_xor(s, m);
    if (s2 == 0) h4pt[b * 8 + o] = s + f1b[o];
}

// ---------------------------------------------------------------------------
// DLT (8x8 fp64 solve, partial pivoting) + 3x3 inverse -> Hinv fp64
// ---------------------------------------------------------------------------
__global__ void dlt_kernel(const float* __restrict__ h4pt, const float* __restrict__ corner,
                           double* __restrict__ hinv)
{
    int b = threadIdx.x;
    if (b >= 64) return;
    double U[4], V[4], Ud[4], Vd[4];
    for (int jq = 0; jq < 4; jq++) {
        U[jq] = (double)corner[b * 8 + 2 * jq];
        V[jq] = (double)corner[b * 8 + 2 * jq + 1];
        Ud[jq] = U[jq] + (double)h4pt[b * 8 + 2 * jq];
        Vd[jq] = V[jq] + (double)h4pt[b * 8 + 2 * jq + 1];
    }
    double A[8][9];
    for (int jq = 0; jq < 4; jq++) {
        double* r0 = A[2 * jq];
        double* r1 = A[2 * jq + 1];
        r0[0] = 0;     r0[1] = 0;     r0[2] = 0;
        r0[3] = -U[jq]; r0[4] = V[jq]; r0[5] = -1;
        r0[6] = Vd[jq] * U[jq]; r0[7] = Vd[jq] * V[jq]; r0[8] = -Vd[jq];
        r1[0] = U[jq]; r1[1] = V[jq]; r1[2] = 1;
        r1[3] = 0;     r1[4] = 0;     r1[5] = 0;
        r1[6] = -Ud[jq] * U[jq]; r1[7] = -Ud[jq] * V[jq]; r1[8] = Ud[jq];
    }
    for (int col = 0; col < 8; col++) {
        int piv = col; double mx = fabs(A[col][col]);
        for (int r = col + 1; r < 8; r++) {
            double v = fabs(A[r][col]);
            if (v > mx) { mx = v; piv = r; }
        }
        if (piv != col)
            for (int cc = col; cc < 9; cc++) { double tmp = A[col][cc]; A[col][cc] = A[piv][cc]; A[piv][cc] = tmp; }
        double inv = 1.0 / A[col][col];
        for (int r = col + 1; r < 8; r++) {
            double f = A[r][col] * inv;
            for (int cc = col; cc < 9; cc++) A[r][cc] -= f * A[col][cc];
        }
    }
    double h[9];
    for (int r = 7; r >= 0; r--) {
        double s = A[r][8];
        for (int cc = r + 1; cc < 8; cc++) s -= A[r][cc] * h[cc];
        h[r] = s / A[r][r];
    }
    h[8] = 1.0;
    double a = h[0], bb = h[1], cq = h[2], d = h[3], e = h[4], f = h[5], g = h[6], hh = h[7], iq = h[8];
    double C00 = e * iq - f * hh, C01 = cq * hh - bb * iq, C02 = bb * f - cq * e;
    double C10 = f * g - d * iq,  C11 = a * iq - cq * g,   C12 = cq * d - a * f;
    double C20 = d * hh - e * g,  C21 = bb * g - a * hh,   C22 = a * e - bb * d;
    double det = a * C00 + bb * C10 + cq * C20;
    double idet = 1.0 / det;
    double* o = hinv + b * 9;
    o[0] = C00 * idet; o[1] = C01 * idet; o[2] = C02 * idet;
    o[3] = C10 * idet; o[4] = C11 * idet; o[5] = C12 * idet;
    o[6] = C20 * idet; o[7] = C21 * idet; o[8] = C22 * idet;
}

// ---------------------------------------------------------------------------
// Perspective warp + bilinear (coords fp64, gather fp32)
// ---------------------------------------------------------------------------
__global__ void warp_kernel(const float* __restrict__ img, const double* __restrict__ hinv,
                            float* __restrict__ out)
{
    int b = blockIdx.y;
    int pix = blockIdx.x * 256 + threadIdx.x;
    int y = pix >> 7, x = pix & 127;
    const double* h = hinv + b * 9;
    double X = (double)x, Y = (double)y;
    double p0 = h[0] * X + h[1] * Y + h[2];
    double p1 = h[3] * X + h[4] * Y + h[5];
    double p2 = h[6] * X + h[7] * Y + h[8];
    double xs = p0 / p2, ys = p1 / p2;
    double x0d = floor(xs), y0d = floor(ys);
    double wx = xs - x0d, wy = ys - y0d;
    int x0 = (int)x0d, y0 = (int)y0d;
    const float* im = img + (size_t)b * 240 * 320;
    auto gat = [&](int yi, int xi) -> double {
        bool valid = (xi >= 0) & (xi < 320) & (yi >= 0) & (yi < 240);
        int yc = yi < 0 ? 0 : (yi > 239 ? 239 : yi);
        int xc = xi < 0 ? 0 : (xi > 319 ? 319 : xi);
        double v = (double)im[yc * 320 + xc];
        return valid ? v : 0.0;
    };
    double v00 = gat(y0, x0),     v01 = gat(y0, x0 + 1);
    double v10 = gat(y0 + 1, x0), v11 = gat(y0 + 1, x0 + 1);
    double r = v00 * (1 - wx) * (1 - wy) + v01 * wx * (1 - wy)
             + v10 * (1 - wx) * wy       + v11 * wx * wy;
    out[((size_t)b << 14) + pix] = (float)r;
}

// ---------------------------------------------------------------------------
// launch
// ---------------------------------------------------------------------------
extern "C" void kernel_launch(void* const* d_in, const int* in_sizes, int n_in,
                              void* d_out, int out_size, void* d_ws, size_t ws_size,
                              hipStream_t stream)
{
    const float* TI1     = (const float*)d_in[1];
    const float* TImgA   = (const float*)d_in[2];
    const float* TCorner = (const float*)d_in[3];
    const float* w[8], *cbp[8], *sp[8], *tp[8];
    for (int l = 0; l < 8; l++) {
        w[l]   = (const float*)d_in[4 + 4 * l];
        cbp[l] = (const float*)d_in[5 + 4 * l];
        sp[l]  = (const float*)d_in[6 + 4 * l];
        tp[l]  = (const float*)d_in[7 + 4 * l];
    }
    const float* fcw = (const float*)d_in[36];
    const float* fcb = (const float*)d_in[37];
    const float* f1w = (const float*)d_in[38];
    const float* f1b = (const float*)d_in[39];

    char* base = (char*)d_ws;
    unsigned short* A  = (unsigned short*)(base);                    // 8,388,608 B (4 img 128^2 x64)
    unsigned short* Bb = (unsigned short*)(base + 8388608);          // 33,554,432 B
    unsigned short* Cc = (unsigned short*)(base + 8388608 + 33554432);
    unsigned short* whiA = (unsigned short*)(base + 8388608 + 2*33554432);          // 626688 elems
    unsigned short* wloA = (unsigned short*)(base + 8388608 + 2*33554432 + 1253376);
    float*  feat = (float*) (base + 8388608 + 2*33554432 + 2*1253376);
    float*  fc1o = feat + 64 * 512;
    float*  h4pt = fc1o + 64 * 1024;
    double* hinv = (double*)(h4pt + 512);
    float*  outp = (float*)d_out;

    // weight transforms for conv2..conv8
    const int CINS[7]  = {64, 64, 64, 64, 128, 128, 128};
    const int COUTS[7] = {64, 64, 64, 128, 128, 128, 128};
    int wofs[8]; wofs[0] = 0;
    for (int l = 0; l < 7; l++) wofs[l + 1] = wofs[l] + 9 * COUTS[l] * CINS[l];
    for (int l = 0; l < 7; l++) {
        int n = 9 * COUTS[l] * CINS[l];
        wtrans<<<(n + 255) / 256, 256, 0, stream>>>(w[l + 1], whiA + wofs[l], wloA + wofs[l],
                                                    COUTS[l], CINS[l]);
    }

    // conv1 + conv2 over 16 chunks of 4 images
    for (int ch = 0; ch < 16; ch++) {
        conv1_kernel<<<dim3(64, 4), 256, 0, stream>>>(
            TI1 + (size_t)ch * 4 * 2 * 128 * 128, w[0], cbp[0], sp[0], tp[0], A);
        conv_mfma<64, 64, 128, 128, 2, 32><<<dim3(128, 1, 4), 256, 0, stream>>>(
            A, whiA + wofs[0], wloA + wofs[0], cbp[1], sp[1], tp[1],
            Bb + (size_t)ch * 4 * 64 * 64 * 64);
    }
    // conv3..conv8 full batch
    conv_mfma<64, 64, 64, 64, 1, 32><<<dim3(32, 1, 64), 256, 0, stream>>>(
        Bb, whiA + wofs[1], wloA + wofs[1], cbp[2], sp[2], tp[2], Cc);
    conv_mfma<64, 64, 64, 64, 2, 32><<<dim3(32, 1, 64), 256, 0, stream>>>(
        Cc, whiA + wofs[2], wloA + wofs[2], cbp[3], sp[3], tp[3], A);
    conv_mfma<64, 128, 32, 32, 1, 32><<<dim3(8, 2, 64), 256, 0, stream>>>(
        A, whiA + wofs[3], wloA + wofs[3], cbp[4], sp[4], tp[4], Bb);
    conv_mfma<128, 128, 32, 32, 2, 32><<<dim3(8, 2, 64), 256, 0, stream>>>(
        Bb, whiA + wofs[4], wloA + wofs[4], cbp[5], sp[5], tp[5], Cc);
    conv_mfma<128, 128, 16, 16, 1, 16><<<dim3(2, 2, 64), 256, 0, stream>>>(
        Cc, whiA + wofs[5], wloA + wofs[5], cbp[6], sp[6], tp[6], A);
    conv_mfma<128, 128, 16, 16, 1, 16><<<dim3(2, 2, 64), 256, 0, stream>>>(
        A, whiA + wofs[6], wloA + wofs[6], cbp[7], sp[7], tp[7], Bb);

    pool6_kernel<<<128, 256, 0, stream>>>(Bb, feat);
    fc1_kernel<<<dim3(4, 64), 256, 0, stream>>>(feat, fcw, fcb, fc1o);
    fc2_kernel<<<64, 256, 0, stream>>>(fc1o, f1w, f1b, h4pt);
    dlt_kernel<<<1, 64, 0, stream>>>(h4pt, TCorner, hinv);
    warp_kernel<<<dim3(64, 64), 256, 0, stream>>>(TImgA, hinv, outp);
}

// Round 3
// 798.151 us; speedup vs baseline: 5.1777x; 1.1647x over previous
//
#include <hip/hip_runtime.h>
#include <math.h>

typedef __attribute__((ext_vector_type(4))) float f32x4;
typedef __attribute__((ext_vector_type(8))) short sh8;

__device__ __forceinline__ float bf2f(unsigned short u){
    union { unsigned int i; float f; } v; v.i = ((unsigned)u) << 16; return v.f;
}
__device__ __forceinline__ unsigned short f2bf(float f){
    union { float f; unsigned int i; } v; v.f = f;
    unsigned int x = v.i;
    x += 0x7fff + ((x >> 16) & 1);   // RNE; inputs finite
    return (unsigned short)(x >> 16);
}

// ---------------------------------------------------------------------------
// Weight transform: w [COUT][CIN][3][3] fp32 -> wT{hi,lo} [tap][COUT][CIN] bf16
// ---------------------------------------------------------------------------
__global__ void wtrans(const float* __restrict__ w, unsigned short* __restrict__ whi,
                       unsigned short* __restrict__ wlo, int COUT, int CIN)
{
    int e = blockIdx.x * 256 + threadIdx.x;
    int n = COUT * CIN * 9;
    if (e >= n) return;
    int tap = e % 9, rest = e / 9;
    int ci = rest % CIN, co = rest / CIN;
    float v = w[e];
    unsigned short hi = f2bf(v);
    unsigned short lo = f2bf(v - bf2f(hi));
    int dst = (tap * COUT + co) * CIN + ci;
    whi[dst] = hi; wlo[dst] = lo;
}

// ---------------------------------------------------------------------------
// conv1: Cin=2 fp32 direct conv + BN + ReLU -> NHWC bf16 out
// ---------------------------------------------------------------------------
__global__ __launch_bounds__(256) void conv1_kernel(
    const float* __restrict__ in, const float* __restrict__ w,
    const float* __restrict__ cb, const float* __restrict__ sc,
    const float* __restrict__ tb, unsigned short* __restrict__ out)
{
    __shared__ float s_w[18 * 64];        // [ci*9+k][co]
    __shared__ float s_in[2][18 * 20];    // halo 18x18, stride 20

    const int tid = threadIdx.x;
    const int b = blockIdx.y;
    const int tile = blockIdx.x;          // 64 tiles of 16x16
    const int ty = tile >> 3, tx = tile & 7;
    const int y0 = ty * 16, x0 = tx * 16;

    for (int idx = tid; idx < 1152; idx += 256) {
        int co = idx & 63, kk2 = idx >> 6;
        s_w[kk2 * 64 + co] = w[co * 18 + kk2];
    }
    for (int idx = tid; idx < 2 * 324; idx += 256) {
        int ci = idx / 324, rem = idx % 324;
        int r = rem / 18, c = rem % 18;
        int gy = y0 + r - 1, gx = x0 + c - 1;
        float v = 0.f;
        if (gy >= 0 && gy < 128 && gx >= 0 && gx < 128)
            v = in[((size_t)(b * 2 + ci) * 128 + gy) * 128 + gx];
        s_in[ci][r * 20 + c] = v;
    }
    __syncthreads();

    const int cog = tid >> 5;
    const int slot = tid & 31;
    const int sy = slot >> 2, sx = slot & 3;

    float p[2][4][6];
#pragma unroll
    for (int ci = 0; ci < 2; ci++)
#pragma unroll
        for (int r = 0; r < 4; r++)
#pragma unroll
            for (int c = 0; c < 6; c++)
                p[ci][r][c] = s_in[ci][(2 * sy + r) * 20 + 4 * sx + c];

    float acc[2][4][8];
#pragma unroll
    for (int r = 0; r < 2; r++)
#pragma unroll
        for (int c = 0; c < 4; c++)
#pragma unroll
            for (int o = 0; o < 8; o++) acc[r][c][o] = 0.f;

#pragma unroll
    for (int kk2 = 0; kk2 < 18; kk2++) {
        const int ci = kk2 / 9, k = kk2 % 9;
        const int ky = k / 3, kx = k % 3;
        float wv[8];
#pragma unroll
        for (int q = 0; q < 2; q++) {
            f32x4 w4 = *(const f32x4*)(&s_w[kk2 * 64 + cog * 8 + q * 4]);
#pragma unroll
            for (int z = 0; z < 4; z++) wv[q * 4 + z] = w4[z];
        }
#pragma unroll
        for (int r = 0; r < 2; r++)
#pragma unroll
            for (int c = 0; c < 4; c++) {
                float pv = p[ci][r + ky][c + kx];
#pragma unroll
                for (int o = 0; o < 8; o++) acc[r][c][o] += pv * wv[o];
            }
    }

    float bb[8], ss[8], tt[8];
#pragma unroll
    for (int o = 0; o < 8; o++) { bb[o] = cb[cog*8+o]; ss[o] = sc[cog*8+o]; tt[o] = tb[cog*8+o]; }
#pragma unroll
    for (int r = 0; r < 2; r++)
#pragma unroll
        for (int c = 0; c < 4; c++) {
            unsigned short ov[8];
#pragma unroll
            for (int o = 0; o < 8; o++)
                ov[o] = f2bf(fmaxf((acc[r][c][o] + bb[o]) * ss[o] + tt[o], 0.f));
            int py = y0 + 2 * sy + r, px = x0 + 4 * sx + c;
            *(sh8*)(out + ((size_t)(b * 128 + py) * 128 + px) * 64 + cog * 8) = *(sh8*)ov;
        }
}

// ---------------------------------------------------------------------------
// MFMA implicit-GEMM conv3x3 SAME + BN + ReLU (+ fused 2x2 maxpool)
// in/out NHWC bf16; weights [tap][COUT][CIN] bf16 hi/lo (2-term split)
// block 256 = 4 waves (2 pixgrp x 2 coutgrp); tile 128 px x 64 couts
// K-loop: 18 steps/chunk (9 taps x K=32), B-frags software-pipelined depth-3
// ---------------------------------------------------------------------------
template<int CIN, int COUT, int HI, int WI, int POOL, int TW>
__global__ __launch_bounds__(256, 2) void conv_mfma(
    const unsigned short* __restrict__ in,
    const unsigned short* __restrict__ whi, const unsigned short* __restrict__ wlo,
    const float* __restrict__ cb, const float* __restrict__ sc,
    const float* __restrict__ tb, unsigned short* __restrict__ out)
{
    constexpr int TH = 128 / TW;
    constexpr int HALW = TW + 2, HALH = TH + 2;
    constexpr int NPIX = HALW * HALH;
    constexpr int CHUNKS = CIN / 64;
    constexpr int TILESX = WI / TW;
    constexpr int HO = HI / POOL, WO = WI / POOL;
    constexpr int ST = 72;               // ushorts per pixel (144B) -> 2-way bank alias only
    constexpr int NK = 18;               // K-steps per 64-cin chunk

    __shared__ __align__(16) unsigned short lds[NPIX * ST];

    const int tid = threadIdx.x;
    const int lane = tid & 63;
    const int i = lane & 15, j = lane >> 4;
    const int wv_ = tid >> 6;
    const int pg = wv_ & 1, cg = wv_ >> 1;
    const int tile = blockIdx.x;
    const int ty = tile / TILESX, tx = tile % TILESX;
    const int y0 = ty * TH, x0 = tx * TW;
    const int cogrp = blockIdx.y;
    const int b = blockIdx.z;

    f32x4 acc[4][2];
#pragma unroll
    for (int pf = 0; pf < 4; pf++)
#pragma unroll
        for (int cf = 0; cf < 2; cf++) acc[pf][cf] = (f32x4){0.f, 0.f, 0.f, 0.f};

    for (int c = 0; c < CHUNKS; c++) {
        if (c) __syncthreads();
        // ---- stage halo tile: NPIX pixels x 64 cin, zero-padded ----
        for (int u = tid; u < NPIX * 8; u += 256) {
            int hp = u >> 3, c16 = u & 7;
            int hy = hp / HALW, hx = hp % HALW;
            int gy = y0 + hy - 1, gx = x0 + hx - 1;
            sh8 v = (sh8){0,0,0,0,0,0,0,0};
            if (gy >= 0 && gy < HI && gx >= 0 && gx < WI)
                v = *(const sh8*)(in + ((size_t)(b * HI + gy) * WI + gx) * CIN + c * 64 + c16 * 8);
            *(sh8*)(&lds[hp * ST + c16 * 8]) = v;
        }

        // ---- wave-invariant weight bases for this chunk ----
        const unsigned short* wbh = whi + ((size_t)(cogrp * 64 + cg * 32 + i)) * CIN + c * 64 + j * 8;
        const unsigned short* wbl = wlo + ((size_t)(cogrp * 64 + cg * 32 + i)) * CIN + c * 64 + j * 8;

        sh8 wb[4][4];   // [ring slot][cf*2 + hilo] — all indices compile-time (full unroll)
        auto loadB = [&](int slot, int ks2) {
            const int tap = ks2 >> 1, kk = ks2 & 1;
            const size_t off = (size_t)tap * COUT * CIN + kk * 32;
#pragma unroll
            for (int cf = 0; cf < 2; cf++) {
                wb[slot][cf * 2 + 0] = *(const sh8*)(wbh + off + (size_t)cf * 16 * CIN);
                wb[slot][cf * 2 + 1] = *(const sh8*)(wbl + off + (size_t)cf * 16 * CIN);
            }
        };
        // prefetch 3 K-steps (issues overlap the staging barrier)
        loadB(0, 0); loadB(1, 1); loadB(2, 2);
        __syncthreads();

#pragma unroll
        for (int ks = 0; ks < NK; ks++) {
            if (ks + 3 < NK) loadB((ks + 3) & 3, ks + 3);
            const int tap = ks >> 1, kk = ks & 1;
            const int ky = tap / 3, kx = tap % 3;
            sh8 a[4];
#pragma unroll
            for (int pf = 0; pf < 4; pf++) {
                const int nf = pg * 4 + pf;
                int hy2, hx2;
                if (TW == 32) { hy2 = (nf >> 1) + ky; hx2 = (nf & 1) * 16 + i + kx; }
                else          { hy2 = nf + ky;        hx2 = i + kx; }
                a[pf] = *(const sh8*)(&lds[(hy2 * HALW + hx2) * ST + kk * 32 + j * 8]);
            }
#pragma unroll
            for (int pf = 0; pf < 4; pf++)
#pragma unroll
                for (int cf = 0; cf < 2; cf++) {
                    acc[pf][cf] = __builtin_amdgcn_mfma_f32_16x16x32_bf16(a[pf], wb[ks & 3][cf * 2 + 0], acc[pf][cf], 0, 0, 0);
                    acc[pf][cf] = __builtin_amdgcn_mfma_f32_16x16x32_bf16(a[pf], wb[ks & 3][cf * 2 + 1], acc[pf][cf], 0, 0, 0);
                }
        }
    }

    // ---- epilogue: BN + ReLU (+pool) ; D: col(i)=cout, row(j*4+r)=pixel ----
    const int cbase = cogrp * 64 + cg * 32;
#pragma unroll
    for (int cf = 0; cf < 2; cf++) {
        const int co = cbase + cf * 16 + i;
        const float b3 = cb[co], s3 = sc[co], t3 = tb[co];
        if (POOL == 1) {
#pragma unroll
            for (int pf = 0; pf < 4; pf++) {
                const int nf = pg * 4 + pf;
                int py, pxb;
                if (TW == 32) { py = nf >> 1; pxb = (nf & 1) * 16; }
                else          { py = nf;      pxb = 0; }
#pragma unroll
                for (int r = 0; r < 4; r++) {
                    float v = fmaxf((acc[pf][cf][r] + b3) * s3 + t3, 0.f);
                    int px = pxb + j * 4 + r;
                    out[((size_t)(b * HO + y0 + py) * WO + x0 + px) * COUT + co] = f2bf(v);
                }
            }
        } else if constexpr (POOL == 2 && TW == 32) {
#pragma unroll
            for (int half = 0; half < 2; half++) {
                const int pfA = half, pfB = 2 + half;
#pragma unroll
                for (int r2 = 0; r2 < 2; r2++) {
                    float vA0 = fmaxf((acc[pfA][cf][2*r2]   + b3) * s3 + t3, 0.f);
                    float vA1 = fmaxf((acc[pfA][cf][2*r2+1] + b3) * s3 + t3, 0.f);
                    float vB0 = fmaxf((acc[pfB][cf][2*r2]   + b3) * s3 + t3, 0.f);
                    float vB1 = fmaxf((acc[pfB][cf][2*r2+1] + b3) * s3 + t3, 0.f);
                    float v = fmaxf(fmaxf(vA0, vA1), fmaxf(vB0, vB1));
                    int pox = (x0 >> 1) + half * 8 + j * 2 + r2;
                    int poy = (y0 >> 1) + pg;
                    out[((size_t)(b * HO + poy) * WO + pox) * COUT + co] = f2bf(v);
                }
            }
        }
    }
}

// ---------------------------------------------------------------------------
// 6x6/6 maxpool on NHWC bf16 (64,16,16,128) -> feat fp32 [b][c*4+oy*2+ox]
// ---------------------------------------------------------------------------
__global__ void pool6_kernel(const unsigned short* __restrict__ in, float* __restrict__ out)
{
    int t = blockIdx.x * 256 + threadIdx.x;
    if (t >= 64 * 128 * 4) return;
    int ox = t & 1, oy = (t >> 1) & 1, c = (t >> 2) & 127, b = t >> 9;
    const unsigned short* p = in + ((size_t)(b * 16 + oy * 6) * 16 + ox * 6) * 128 + c;
    float m = -INFINITY;
#pragma unroll
    for (int r = 0; r < 6; r++)
#pragma unroll
        for (int cc = 0; cc < 6; cc++) m = fmaxf(m, bf2f(p[(r * 16 + cc) * 128]));
    out[(size_t)b * 512 + c * 4 + oy * 2 + ox] = m;
}

// ---------------------------------------------------------------------------
// FC1 / FC2 / DLT / warp (unchanged)
// ---------------------------------------------------------------------------
__global__ void fc1_kernel(const float* __restrict__ flat, const float* __restrict__ fcw,
                           const float* __restrict__ fcb, float* __restrict__ out1)
{
    int b = blockIdx.y;
    int jj = blockIdx.x * 256 + threadIdx.x;
    const f32x4* f = (const f32x4*)(flat + (size_t)b * 512);
    const f32x4* w = (const f32x4*)(fcw + (size_t)jj * 512);
    float s = fcb[jj];
    for (int k = 0; k < 128; k++) {
        f32x4 a = f[k], ww = w[k];
        s += a[0]*ww[0] + a[1]*ww[1] + a[2]*ww[2] + a[3]*ww[3];
    }
    out1[(size_t)b * 1024 + jj] = fmaxf(s, 0.f);
}

__global__ void fc2_kernel(const float* __restrict__ out1, const float* __restrict__ f1w,
                           const float* __restrict__ f1b, float* __restrict__ h4pt)
{
    int b = blockIdx.x;
    int o = threadIdx.x >> 5, s2 = threadIdx.x & 31;
    const float* pa = out1 + (size_t)b * 1024;
    const float* pw = f1w + (size_t)o * 1024;
    float s = 0.f;
    for (int k = s2; k < 1024; k += 32) s += pa[k] * pw[k];
#pragma unroll
    for (int m = 16; m; m >>= 1) s += __shfl_xor(s, m);
    if (s2 == 0) h4pt[b * 8 + o] = s + f1b[o];
}

__global__ void dlt_kernel(const float* __restrict__ h4pt, const float* __restrict__ corner,
                           double* __restrict__ hinv)
{
    int b = threadIdx.x;
    if (b >= 64) return;
    double U[4], V[4], Ud[4], Vd[4];
    for (int jq = 0; jq < 4; jq++) {
        U[jq] = (double)corner[b * 8 + 2 * jq];
        V[jq] = (double)corner[b * 8 + 2 * jq + 1];
        Ud[jq] = U[jq] + (double)h4pt[b * 8 + 2 * jq];
        Vd[jq] = V[jq] + (double)h4pt[b * 8 + 2 * jq + 1];
    }
    double A[8][9];
    for (int jq = 0; jq < 4; jq++) {
        double* r0 = A[2 * jq];
        double* r1 = A[2 * jq + 1];
        r0[0] = 0;     r0[1] = 0;     r0[2] = 0;
        r0[3] = -U[jq]; r0[4] = V[jq]; r0[5] = -1;
        r0[6] = Vd[jq] * U[jq]; r0[7] = Vd[jq] * V[jq]; r0[8] = -Vd[jq];
        r1[0] = U[jq]; r1[1] = V[jq]; r1[2] = 1;
        r1[3] = 0;     r1[4] = 0;     r1[5] = 0;
        r1[6] = -Ud[jq] * U[jq]; r1[7] = -Ud[jq] * V[jq]; r1[8] = Ud[jq];
    }
    for (int col = 0; col < 8; col++) {
        int piv = col; double mx = fabs(A[col][col]);
        for (int r = col + 1; r < 8; r++) {
            double v = fabs(A[r][col]);
            if (v > mx) { mx = v; piv = r; }
        }
        if (piv != col)
            for (int cc = col; cc < 9; cc++) { double tmp = A[col][cc]; A[col][cc] = A[piv][cc]; A[piv][cc] = tmp; }
        double inv = 1.0 / A[col][col];
        for (int r = col + 1; r < 8; r++) {
            double f = A[r][col] * inv;
            for (int cc = col; cc < 9; cc++) A[r][cc] -= f * A[col][cc];
        }
    }
    double h[9];
    for (int r = 7; r >= 0; r--) {
        double s = A[r][8];
        for (int cc = r + 1; cc < 8; cc++) s -= A[r][cc] * h[cc];
        h[r] = s / A[r][r];
    }
    h[8] = 1.0;
    double a = h[0], bb = h[1], cq = h[2], d = h[3], e = h[4], f = h[5], g = h[6], hh = h[7], iq = h[8];
    double C00 = e * iq - f * hh, C01 = cq * hh - bb * iq, C02 = bb * f - cq * e;
    double C10 = f * g - d * iq,  C11 = a * iq - cq * g,   C12 = cq * d - a * f;
    double C20 = d * hh - e * g,  C21 = bb * g - a * hh,   C22 = a * e - bb * d;
    double det = a * C00 + bb * C10 + cq * C20;
    double idet = 1.0 / det;
    double* o = hinv + b * 9;
    o[0] = C00 * idet; o[1] = C01 * idet; o[2] = C02 * idet;
    o[3] = C10 * idet; o[4] = C11 * idet; o[5] = C12 * idet;
    o[6] = C20 * idet; o[7] = C21 * idet; o[8] = C22 * idet;
}

__global__ void warp_kernel(const float* __restrict__ img, const double* __restrict__ hinv,
                            float* __restrict__ out)
{
    int b = blockIdx.y;
    int pix = blockIdx.x * 256 + threadIdx.x;
    int y = pix >> 7, x = pix & 127;
    const double* h = hinv + b * 9;
    double X = (double)x, Y = (double)y;
    double p0 = h[0] * X + h[1] * Y + h[2];
    double p1 = h[3] * X + h[4] * Y + h[5];
    double p2 = h[6] * X + h[7] * Y + h[8];
    double xs = p0 / p2, ys = p1 / p2;
    double x0d = floor(xs), y0d = floor(ys);
    double wx = xs - x0d, wy = ys - y0d;
    int x0 = (int)x0d, y0 = (int)y0d;
    const float* im = img + (size_t)b * 240 * 320;
    auto gat = [&](int yi, int xi) -> double {
        bool valid = (xi >= 0) & (xi < 320) & (yi >= 0) & (yi < 240);
        int yc = yi < 0 ? 0 : (yi > 239 ? 239 : yi);
        int xc = xi < 0 ? 0 : (xi > 319 ? 319 : xi);
        double v = (double)im[yc * 320 + xc];
        return valid ? v : 0.0;
    };
    double v00 = gat(y0, x0),     v01 = gat(y0, x0 + 1);
    double v10 = gat(y0 + 1, x0), v11 = gat(y0 + 1, x0 + 1);
    double r = v00 * (1 - wx) * (1 - wy) + v01 * wx * (1 - wy)
             + v10 * (1 - wx) * wy       + v11 * wx * wy;
    out[((size_t)b << 14) + pix] = (float)r;
}

// ---------------------------------------------------------------------------
// launch — ping-pong A<->Bb (2x 33.5 MB), 16-image conv1/conv2 chunks
// total workspace ~70.1 MB (below 78.3 MB proven this round)
// ---------------------------------------------------------------------------
extern "C" void kernel_launch(void* const* d_in, const int* in_sizes, int n_in,
                              void* d_out, int out_size, void* d_ws, size_t ws_size,
                              hipStream_t stream)
{
    const float* TI1     = (const float*)d_in[1];
    const float* TImgA   = (const float*)d_in[2];
    const float* TCorner = (const float*)d_in[3];
    const float* w[8], *cbp[8], *sp[8], *tp[8];
    for (int l = 0; l < 8; l++) {
        w[l]   = (const float*)d_in[4 + 4 * l];
        cbp[l] = (const float*)d_in[5 + 4 * l];
        sp[l]  = (const float*)d_in[6 + 4 * l];
        tp[l]  = (const float*)d_in[7 + 4 * l];
    }
    const float* fcw = (const float*)d_in[36];
    const float* fcb = (const float*)d_in[37];
    const float* f1w = (const float*)d_in[38];
    const float* f1b = (const float*)d_in[39];

    char* base = (char*)d_ws;
    unsigned short* A    = (unsigned short*)(base);                  // 33,554,432 B
    unsigned short* Bb   = (unsigned short*)(base + 33554432);       // 33,554,432 B
    unsigned short* whiA = (unsigned short*)(base + 67108864);       // 1,253,376 B
    unsigned short* wloA = (unsigned short*)(base + 67108864 + 1253376);
    float*  feat = (float*) (base + 67108864 + 2 * 1253376);
    float*  fc1o = feat + 64 * 512;
    float*  h4pt = fc1o + 64 * 1024;
    double* hinv = (double*)(h4pt + 512);
    float*  outp = (float*)d_out;

    // weight transforms for conv2..conv8
    const int CINS[7]  = {64, 64, 64, 64, 128, 128, 128};
    const int COUTS[7] = {64, 64, 64, 128, 128, 128, 128};
    int wofs[8]; wofs[0] = 0;
    for (int l = 0; l < 7; l++) wofs[l + 1] = wofs[l] + 9 * COUTS[l] * CINS[l];
    for (int l = 0; l < 7; l++) {
        int n = 9 * COUTS[l] * CINS[l];
        wtrans<<<(n + 255) / 256, 256, 0, stream>>>(w[l + 1], whiA + wofs[l], wloA + wofs[l],
                                                    COUTS[l], CINS[l]);
    }

    // conv1 + conv2 over 4 chunks of 16 images (A reused per chunk; Bb = full conv2 out)
    for (int ch = 0; ch < 4; ch++) {
        conv1_kernel<<<dim3(64, 16), 256, 0, stream>>>(
            TI1 + (size_t)ch * 16 * 2 * 128 * 128, w[0], cbp[0], sp[0], tp[0], A);
        conv_mfma<64, 64, 128, 128, 2, 32><<<dim3(128, 1, 16), 256, 0, stream>>>(
            A, whiA + wofs[0], wloA + wofs[0], cbp[1], sp[1], tp[1],
            Bb + (size_t)ch * 16 * 64 * 64 * 64);
    }
    // conv3..conv8 full batch, ping-pong Bb <-> A
    conv_mfma<64, 64, 64, 64, 1, 32><<<dim3(32, 1, 64), 256, 0, stream>>>(
        Bb, whiA + wofs[1], wloA + wofs[1], cbp[2], sp[2], tp[2], A);
    conv_mfma<64, 64, 64, 64, 2, 32><<<dim3(32, 1, 64), 256, 0, stream>>>(
        A, whiA + wofs[2], wloA + wofs[2], cbp[3], sp[3], tp[3], Bb);
    conv_mfma<64, 128, 32, 32, 1, 32><<<dim3(8, 2, 64), 256, 0, stream>>>(
        Bb, whiA + wofs[3], wloA + wofs[3], cbp[4], sp[4], tp[4], A);
    conv_mfma<128, 128, 32, 32, 2, 32><<<dim3(8, 2, 64), 256, 0, stream>>>(
        A, whiA + wofs[4], wloA + wofs[4], cbp[5], sp[5], tp[5], Bb);
    conv_mfma<128, 128, 16, 16, 1, 16><<<dim3(2, 2, 64), 256, 0, stream>>>(
        Bb, whiA + wofs[5], wloA + wofs[5], cbp[6], sp[6], tp[6], A);
    conv_mfma<128, 128, 16, 16, 1, 16><<<dim3(2, 2, 64), 256, 0, stream>>>(
        A, whiA + wofs[6], wloA + wofs[6], cbp[7], sp[7], tp[7], Bb);

    pool6_kernel<<<128, 256, 0, stream>>>(Bb, feat);
    fc1_kernel<<<dim3(4, 64), 256, 0, stream>>>(feat, fcw, fcb, fc1o);
    fc2_kernel<<<64, 256, 0, stream>>>(fc1o, f1w, f1b, h4pt);
    dlt_kernel<<<1, 64, 0, stream>>>(h4pt, TCorner, hinv);
    warp_kernel<<<dim3(64, 64), 256, 0, stream>>>(TImgA, hinv, outp);
}

// Round 4
// 458.814 us; speedup vs baseline: 9.0071x; 1.7396x over previous
//
#include <hip/hip_runtime.h>
#include <math.h>

typedef __attribute__((ext_vector_type(4))) float f32x4;
typedef __attribute__((ext_vector_type(8))) short sh8;

__device__ __forceinline__ float bf2f(unsigned short u){
    union { unsigned int i; float f; } v; v.i = ((unsigned)u) << 16; return v.f;
}
__device__ __forceinline__ unsigned short f2bf(float f){
    union { float f; unsigned int i; } v; v.f = f;
    unsigned int x = v.i;
    x += 0x7fff + ((x >> 16) & 1);   // RNE; inputs finite
    return (unsigned short)(x >> 16);
}

// ---------------------------------------------------------------------------
// Merged weight transform for conv2..conv8:
// w [COUT][CIN][3][3] fp32 -> wT{hi,lo} [tap][COUT][CIN] bf16 (hi/lo split)
// ---------------------------------------------------------------------------
struct WTArgs {
    const float* src[7];
    unsigned short* hi[7];
    unsigned short* lo[7];
    int cin[7];
    int start[8];     // prefix element offsets
};

__global__ void wtrans_all(WTArgs a)
{
    int e = blockIdx.x * 256 + threadIdx.x;
    if (e >= a.start[7]) return;
    int l = 0;
    while (e >= a.start[l + 1]) l++;
    int eL = e - a.start[l];
    int CIN = a.cin[l];
    int tap = eL % 9, rest = eL / 9;
    int ci = rest % CIN, co = rest / CIN;
    float v = a.src[l][eL];
    unsigned short hi = f2bf(v);
    unsigned short lo = f2bf(v - bf2f(hi));
    int COUT = (a.start[l + 1] - a.start[l]) / (9 * CIN);
    int dst = (tap * COUT + co) * CIN + ci;
    a.hi[l][dst] = hi; a.lo[l][dst] = lo;
}

// ---------------------------------------------------------------------------
// conv1: Cin=2 fp32 direct conv + BN + ReLU -> NHWC bf16 out
// ---------------------------------------------------------------------------
__global__ __launch_bounds__(256) void conv1_kernel(
    const float* __restrict__ in, const float* __restrict__ w,
    const float* __restrict__ cb, const float* __restrict__ sc,
    const float* __restrict__ tb, unsigned short* __restrict__ out)
{
    __shared__ float s_w[18 * 64];
    __shared__ float s_in[2][18 * 20];

    const int tid = threadIdx.x;
    const int b = blockIdx.y;
    const int tile = blockIdx.x;
    const int ty = tile >> 3, tx = tile & 7;
    const int y0 = ty * 16, x0 = tx * 16;

    for (int idx = tid; idx < 1152; idx += 256) {
        int co = idx & 63, kk2 = idx >> 6;
        s_w[kk2 * 64 + co] = w[co * 18 + kk2];
    }
    for (int idx = tid; idx < 2 * 324; idx += 256) {
        int ci = idx / 324, rem = idx % 324;
        int r = rem / 18, c = rem % 18;
        int gy = y0 + r - 1, gx = x0 + c - 1;
        float v = 0.f;
        if (gy >= 0 && gy < 128 && gx >= 0 && gx < 128)
            v = in[((size_t)(b * 2 + ci) * 128 + gy) * 128 + gx];
        s_in[ci][r * 20 + c] = v;
    }
    __syncthreads();

    const int cog = tid >> 5;
    const int slot = tid & 31;
    const int sy = slot >> 2, sx = slot & 3;

    float p[2][4][6];
#pragma unroll
    for (int ci = 0; ci < 2; ci++)
#pragma unroll
        for (int r = 0; r < 4; r++)
#pragma unroll
            for (int c = 0; c < 6; c++)
                p[ci][r][c] = s_in[ci][(2 * sy + r) * 20 + 4 * sx + c];

    float acc[2][4][8];
#pragma unroll
    for (int r = 0; r < 2; r++)
#pragma unroll
        for (int c = 0; c < 4; c++)
#pragma unroll
            for (int o = 0; o < 8; o++) acc[r][c][o] = 0.f;

#pragma unroll
    for (int kk2 = 0; kk2 < 18; kk2++) {
        const int ci = kk2 / 9, k = kk2 % 9;
        const int ky = k / 3, kx = k % 3;
        float wv[8];
#pragma unroll
        for (int q = 0; q < 2; q++) {
            f32x4 w4 = *(const f32x4*)(&s_w[kk2 * 64 + cog * 8 + q * 4]);
#pragma unroll
            for (int z = 0; z < 4; z++) wv[q * 4 + z] = w4[z];
        }
#pragma unroll
        for (int r = 0; r < 2; r++)
#pragma unroll
            for (int c = 0; c < 4; c++) {
                float pv = p[ci][r + ky][c + kx];
#pragma unroll
                for (int o = 0; o < 8; o++) acc[r][c][o] += pv * wv[o];
            }
    }

    float bb[8], ss[8], tt[8];
#pragma unroll
    for (int o = 0; o < 8; o++) { bb[o] = cb[cog*8+o]; ss[o] = sc[cog*8+o]; tt[o] = tb[cog*8+o]; }
#pragma unroll
    for (int r = 0; r < 2; r++)
#pragma unroll
        for (int c = 0; c < 4; c++) {
            unsigned short ov[8];
#pragma unroll
            for (int o = 0; o < 8; o++)
                ov[o] = f2bf(fmaxf((acc[r][c][o] + bb[o]) * ss[o] + tt[o], 0.f));
            int py = y0 + 2 * sy + r, px = x0 + 4 * sx + c;
            *(sh8*)(out + ((size_t)(b * 128 + py) * 128 + px) * 64 + cog * 8) = *(sh8*)ov;
        }
}

// ---------------------------------------------------------------------------
// MFMA implicit-GEMM conv3x3 + BN + ReLU (+ fused 2x2 maxpool), v3:
// 8 waves (512 thr) = 4 pixgrp x 2 cogrp; tile 256 px x 64 cout.
// A-halo resident in LDS (144B/px stride -> bank-rotation, conflict-free).
// Weights double-buffered in LDS per (tap,kk) step, 2-phase pipeline:
//   iter ks: {global prefetch ks+2 -> reg; ds_write reg(ks+1) -> buf[ks+1];
//             ds_read+16 MFMA from buf[ks]; barrier}
// Weight LDS uses XOR swizzle slot^= (co&3) on BOTH write & read (T2, rule#21).
// ---------------------------------------------------------------------------
template<int CIN, int COUT, int HI, int WI, int POOL, int TW>
__global__ __launch_bounds__(512, 4) void conv_mfma(
    const unsigned short* __restrict__ in,
    const unsigned short* __restrict__ whi, const unsigned short* __restrict__ wlo,
    const float* __restrict__ cb, const float* __restrict__ sc,
    const float* __restrict__ tb, unsigned short* __restrict__ out)
{
    constexpr int TH = 256 / TW;
    constexpr int HALW = TW + 2, HALH = TH + 2;
    constexpr int NPIX = HALW * HALH;
    constexpr int CHUNKS = CIN / 64;
    constexpr int TILESX = WI / TW;
    constexpr int HO = HI / POOL, WO = WI / POOL;
    constexpr int ST = 72;               // ushorts per pixel (144B)
    constexpr int NK = 18;               // (tap,kk) steps per 64-cin chunk

    __shared__ __align__(16) unsigned short lds_A[NPIX * ST];
    __shared__ __align__(16) unsigned short lds_W[2][4096];  // [buf][hilo*2048+co*32+slot*8]

    const int tid = threadIdx.x;
    const int lane = tid & 63;
    const int i = lane & 15, j = lane >> 4;
    const int wv_ = tid >> 6;
    const int pg = wv_ & 3, cg = wv_ >> 2;
    const int tile = blockIdx.x;
    const int ty = tile / TILESX, tx = tile % TILESX;
    const int y0 = ty * TH, x0 = tx * TW;
    const int coBase = blockIdx.y * 64;
    const int b = blockIdx.z;

    // per-thread weight-staging role: 8KB/step over 512 threads = 16B each
    const int hilo = tid >> 8;                  // waves 0-3: hi, 4-7: lo
    const int t8 = tid & 255;
    const int s_s = t8 & 3;                     // physical slot
    const int co_s = t8 >> 2;                   // 0..63
    const int g_s = s_s ^ (co_s & 3);           // source cin-granule (swizzle)
    const unsigned short* wsel = hilo ? wlo : whi;

    f32x4 acc[4][2];
#pragma unroll
    for (int pf = 0; pf < 4; pf++)
#pragma unroll
        for (int cf = 0; cf < 2; cf++) acc[pf][cf] = (f32x4){0.f, 0.f, 0.f, 0.f};

    sh8 reg0, reg1;

    for (int c = 0; c < CHUNKS; c++) {
        if (c) __syncthreads();   // everyone done with prev chunk's LDS

        // ---- stage A halo: NPIX pixels x 64 cin, zero-padded ----
        for (int u = tid; u < NPIX * 8; u += 512) {
            int hp = u >> 3, c16 = u & 7;
            int hy = hp / HALW, hx = hp % HALW;
            int gy = y0 + hy - 1, gx = x0 + hx - 1;
            sh8 v = (sh8){0,0,0,0,0,0,0,0};
            if (gy >= 0 && gy < HI && gx >= 0 && gx < WI)
                v = *(const sh8*)(in + ((size_t)(b * HI + gy) * WI + gx) * CIN + c * 64 + c16 * 8);
            *(sh8*)(&lds_A[hp * ST + c16 * 8]) = v;
        }

        auto LOADW = [&](sh8& dst, int ks) {
            const int tap = ks >> 1, kk = ks & 1;
            dst = *(const sh8*)(wsel + ((size_t)(tap * COUT + coBase + co_s)) * CIN
                                + c * 64 + kk * 32 + g_s * 8);
        };
        auto WRITEW = [&](int bi, const sh8& v) {
            *(sh8*)(&lds_W[bi][hilo * 2048 + co_s * 32 + s_s * 8]) = v;
        };

        LOADW(reg0, 0); LOADW(reg1, 1);
        WRITEW(0, reg0);
        __syncthreads();

#pragma unroll
        for (int ks = 0; ks < NK; ks++) {
            if (ks + 2 < NK) {
                if ((ks & 1) == 0) LOADW(reg0, ks + 2); else LOADW(reg1, ks + 2);
            }
            if (ks + 1 < NK) {
                if (((ks + 1) & 1) == 0) WRITEW(0, reg0); else WRITEW(1, reg1);
            }
            // ---- compute step ks from buf[ks&1] ----
            const int tap = ks >> 1, kk = ks & 1;
            const int ky = tap / 3, kx = tap % 3;
            const int bi = ks & 1;
            sh8 aF[4], bF[4];
#pragma unroll
            for (int pf = 0; pf < 4; pf++) {
                const int nf = pg * 4 + pf;
                int hy2, hx2;
                if (TW == 32) { hy2 = (nf >> 1) + ky; hx2 = (nf & 1) * 16 + i + kx; }
                else          { hy2 = nf + ky;        hx2 = i + kx; }
                aF[pf] = *(const sh8*)(&lds_A[(hy2 * HALW + hx2) * ST + kk * 32 + j * 8]);
            }
#pragma unroll
            for (int cf = 0; cf < 2; cf++)
#pragma unroll
                for (int hl = 0; hl < 2; hl++)
                    bF[cf * 2 + hl] = *(const sh8*)(&lds_W[bi][hl * 2048
                        + (cg * 32 + cf * 16 + i) * 32 + ((j ^ (i & 3)) * 8)]);
            __builtin_amdgcn_s_setprio(1);
#pragma unroll
            for (int pf = 0; pf < 4; pf++)
#pragma unroll
                for (int cf = 0; cf < 2; cf++) {
                    acc[pf][cf] = __builtin_amdgcn_mfma_f32_16x16x32_bf16(aF[pf], bF[cf * 2 + 0], acc[pf][cf], 0, 0, 0);
                    acc[pf][cf] = __builtin_amdgcn_mfma_f32_16x16x32_bf16(aF[pf], bF[cf * 2 + 1], acc[pf][cf], 0, 0, 0);
                }
            __builtin_amdgcn_s_setprio(0);
            if (ks < NK - 1) __syncthreads();
        }
    }

    // ---- epilogue: BN + ReLU (+pool); D: col(i)=cout, row(j*4+r)=pixel ----
#pragma unroll
    for (int cf = 0; cf < 2; cf++) {
        const int co = coBase + cg * 32 + cf * 16 + i;
        const float b3 = cb[co], s3 = sc[co], t3 = tb[co];
        if (POOL == 1) {
#pragma unroll
            for (int pf = 0; pf < 4; pf++) {
                const int nf = pg * 4 + pf;
                int py, pxb;
                if (TW == 32) { py = nf >> 1; pxb = (nf & 1) * 16; }
                else          { py = nf;      pxb = 0; }
#pragma unroll
                for (int r = 0; r < 4; r++) {
                    float v = fmaxf((acc[pf][cf][r] + b3) * s3 + t3, 0.f);
                    int px = pxb + j * 4 + r;
                    out[((size_t)(b * HO + y0 + py) * WO + x0 + px) * COUT + co] = f2bf(v);
                }
            }
        } else if constexpr (POOL == 2 && TW == 32) {
            // wave rows 2pg,2pg+1 -> pooled row pg; pf pairs (h, h+2) share a row pair
#pragma unroll
            for (int h = 0; h < 2; h++) {
                const int pfA = h, pfB = 2 + h;
#pragma unroll
                for (int r2 = 0; r2 < 2; r2++) {
                    float vA0 = fmaxf((acc[pfA][cf][2*r2]   + b3) * s3 + t3, 0.f);
                    float vA1 = fmaxf((acc[pfA][cf][2*r2+1] + b3) * s3 + t3, 0.f);
                    float vB0 = fmaxf((acc[pfB][cf][2*r2]   + b3) * s3 + t3, 0.f);
                    float vB1 = fmaxf((acc[pfB][cf][2*r2+1] + b3) * s3 + t3, 0.f);
                    float v = fmaxf(fmaxf(vA0, vA1), fmaxf(vB0, vB1));
                    int pox = (x0 >> 1) + h * 8 + j * 2 + r2;
                    int poy = (y0 >> 1) + pg;
                    out[((size_t)(b * HO + poy) * WO + pox) * COUT + co] = f2bf(v);
                }
            }
        }
    }
}

// ---------------------------------------------------------------------------
// 6x6/6 maxpool on NHWC bf16 (64,16,16,128) -> feat fp32 [b][c*4+oy*2+ox]
// ---------------------------------------------------------------------------
__global__ void pool6_kernel(const unsigned short* __restrict__ in, float* __restrict__ out)
{
    int t = blockIdx.x * 256 + threadIdx.x;
    if (t >= 64 * 128 * 4) return;
    int ox = t & 1, oy = (t >> 1) & 1, c = (t >> 2) & 127, b = t >> 9;
    const unsigned short* p = in + ((size_t)(b * 16 + oy * 6) * 16 + ox * 6) * 128 + c;
    float m = -INFINITY;
#pragma unroll
    for (int r = 0; r < 6; r++)
#pragma unroll
        for (int cc = 0; cc < 6; cc++) m = fmaxf(m, bf2f(p[(r * 16 + cc) * 128]));
    out[(size_t)b * 512 + c * 4 + oy * 2 + ox] = m;
}

// ---------------------------------------------------------------------------
// FC1 / FC2 / DLT / warp
// ---------------------------------------------------------------------------
__global__ void fc1_kernel(const float* __restrict__ flat, const float* __restrict__ fcw,
                           const float* __restrict__ fcb, float* __restrict__ out1)
{
    int b = blockIdx.y;
    int jj = blockIdx.x * 256 + threadIdx.x;
    const f32x4* f = (const f32x4*)(flat + (size_t)b * 512);
    const f32x4* w = (const f32x4*)(fcw + (size_t)jj * 512);
    float s = fcb[jj];
    for (int k = 0; k < 128; k++) {
        f32x4 a = f[k], ww = w[k];
        s += a[0]*ww[0] + a[1]*ww[1] + a[2]*ww[2] + a[3]*ww[3];
    }
    out1[(size_t)b * 1024 + jj] = fmaxf(s, 0.f);
}

__global__ void fc2_kernel(const float* __restrict__ out1, const float* __restrict__ f1w,
                           const float* __restrict__ f1b, float* __restrict__ h4pt)
{
    int b = blockIdx.x;
    int o = threadIdx.x >> 5, s2 = threadIdx.x & 31;
    const float* pa = out1 + (size_t)b * 1024;
    const float* pw = f1w + (size_t)o * 1024;
    float s = 0.f;
    for (int k = s2; k < 1024; k += 32) s += pa[k] * pw[k];
#pragma unroll
    for (int m = 16; m; m >>= 1) s += __shfl_xor(s, m);
    if (s2 == 0) h4pt[b * 8 + o] = s + f1b[o];
}

__global__ void dlt_kernel(const float* __restrict__ h4pt, const float* __restrict__ corner,
                           double* __restrict__ hinv)
{
    int b = threadIdx.x;
    if (b >= 64) return;
    double U[4], V[4], Ud[4], Vd[4];
    for (int jq = 0; jq < 4; jq++) {
        U[jq] = (double)corner[b * 8 + 2 * jq];
        V[jq] = (double)corner[b * 8 + 2 * jq + 1];
        Ud[jq] = U[jq] + (double)h4pt[b * 8 + 2 * jq];
        Vd[jq] = V[jq] + (double)h4pt[b * 8 + 2 * jq + 1];
    }
    double A[8][9];
    for (int jq = 0; jq < 4; jq++) {
        double* r0 = A[2 * jq];
        double* r1 = A[2 * jq + 1];
        r0[0] = 0;     r0[1] = 0;     r0[2] = 0;
        r0[3] = -U[jq]; r0[4] = V[jq]; r0[5] = -1;
        r0[6] = Vd[jq] * U[jq]; r0[7] = Vd[jq] * V[jq]; r0[8] = -Vd[jq];
        r1[0] = U[jq]; r1[1] = V[jq]; r1[2] = 1;
        r1[3] = 0;     r1[4] = 0;     r1[5] = 0;
        r1[6] = -Ud[jq] * U[jq]; r1[7] = -Ud[jq] * V[jq]; r1[8] = Ud[jq];
    }
    for (int col = 0; col < 8; col++) {
        int piv = col; double mx = fabs(A[col][col]);
        for (int r = col + 1; r < 8; r++) {
            double v = fabs(A[r][col]);
            if (v > mx) { mx = v; piv = r; }
        }
        if (piv != col)
            for (int cc = col; cc < 9; cc++) { double tmp = A[col][cc]; A[col][cc] = A[piv][cc]; A[piv][cc] = tmp; }
        double inv = 1.0 / A[col][col];
        for (int r = col + 1; r < 8; r++) {
            double f = A[r][col] * inv;
            for (int cc = col; cc < 9; cc++) A[r][cc] -= f * A[col][cc];
        }
    }
    double h[9];
    for (int r = 7; r >= 0; r--) {
        double s = A[r][8];
        for (int cc = r + 1; cc < 8; cc++) s -= A[r][cc] * h[cc];
        h[r] = s / A[r][r];
    }
    h[8] = 1.0;
    double a = h[0], bb = h[1], cq = h[2], d = h[3], e = h[4], f = h[5], g = h[6], hh = h[7], iq = h[8];
    double C00 = e * iq - f * hh, C01 = cq * hh - bb * iq, C02 = bb * f - cq * e;
    double C10 = f * g - d * iq,  C11 = a * iq - cq * g,   C12 = cq * d - a * f;
    double C20 = d * hh - e * g,  C21 = bb * g - a * hh,   C22 = a * e - bb * d;
    double det = a * C00 + bb * C10 + cq * C20;
    double idet = 1.0 / det;
    double* o = hinv + b * 9;
    o[0] = C00 * idet; o[1] = C01 * idet; o[2] = C02 * idet;
    o[3] = C10 * idet; o[4] = C11 * idet; o[5] = C12 * idet;
    o[6] = C20 * idet; o[7] = C21 * idet; o[8] = C22 * idet;
}

__global__ void warp_kernel(const float* __restrict__ img, const double* __restrict__ hinv,
                            float* __restrict__ out)
{
    int b = blockIdx.y;
    int pix = blockIdx.x * 256 + threadIdx.x;
    int y = pix >> 7, x = pix & 127;
    const double* h = hinv + b * 9;
    double X = (double)x, Y = (double)y;
    double p0 = h[0] * X + h[1] * Y + h[2];
    double p1 = h[3] * X + h[4] * Y + h[5];
    double p2 = h[6] * X + h[7] * Y + h[8];
    double xs = p0 / p2, ys = p1 / p2;
    double x0d = floor(xs), y0d = floor(ys);
    double wx = xs - x0d, wy = ys - y0d;
    int x0 = (int)x0d, y0 = (int)y0d;
    const float* im = img + (size_t)b * 240 * 320;
    auto gat = [&](int yi, int xi) -> double {
        bool valid = (xi >= 0) & (xi < 320) & (yi >= 0) & (yi < 240);
        int yc = yi < 0 ? 0 : (yi > 239 ? 239 : yi);
        int xc = xi < 0 ? 0 : (xi > 319 ? 319 : xi);
        double v = (double)im[yc * 320 + xc];
        return valid ? v : 0.0;
    };
    double v00 = gat(y0, x0),     v01 = gat(y0, x0 + 1);
    double v10 = gat(y0 + 1, x0), v11 = gat(y0 + 1, x0 + 1);
    double r = v00 * (1 - wx) * (1 - wy) + v01 * wx * (1 - wy)
             + v10 * (1 - wx) * wy       + v11 * wx * wy;
    out[((size_t)b << 14) + pix] = (float)r;
}

// ---------------------------------------------------------------------------
// launch — ping-pong A<->Bb (2x 33.5 MB), ~70 MB workspace
// ---------------------------------------------------------------------------
extern "C" void kernel_launch(void* const* d_in, const int* in_sizes, int n_in,
                              void* d_out, int out_size, void* d_ws, size_t ws_size,
                              hipStream_t stream)
{
    const float* TI1     = (const float*)d_in[1];
    const float* TImgA   = (const float*)d_in[2];
    const float* TCorner = (const float*)d_in[3];
    const float* w[8], *cbp[8], *sp[8], *tp[8];
    for (int l = 0; l < 8; l++) {
        w[l]   = (const float*)d_in[4 + 4 * l];
        cbp[l] = (const float*)d_in[5 + 4 * l];
        sp[l]  = (const float*)d_in[6 + 4 * l];
        tp[l]  = (const float*)d_in[7 + 4 * l];
    }
    const float* fcw = (const float*)d_in[36];
    const float* fcb = (const float*)d_in[37];
    const float* f1w = (const float*)d_in[38];
    const float* f1b = (const float*)d_in[39];

    char* base = (char*)d_ws;
    unsigned short* A    = (unsigned short*)(base);
    unsigned short* Bb   = (unsigned short*)(base + 33554432);
    unsigned short* whiA = (unsigned short*)(base + 67108864);
    unsigned short* wloA = (unsigned short*)(base + 67108864 + 1253376);
    float*  feat = (float*) (base + 67108864 + 2 * 1253376);
    float*  fc1o = feat + 64 * 512;
    float*  h4pt = fc1o + 64 * 1024;
    double* hinv = (double*)(h4pt + 512);
    float*  outp = (float*)d_out;

    const int CINS[7]  = {64, 64, 64, 64, 128, 128, 128};
    const int COUTS[7] = {64, 64, 64, 128, 128, 128, 128};
    int wofs[8]; wofs[0] = 0;
    for (int l = 0; l < 7; l++) wofs[l + 1] = wofs[l] + 9 * COUTS[l] * CINS[l];

    WTArgs wa;
    for (int l = 0; l < 7; l++) {
        wa.src[l] = w[l + 1];
        wa.hi[l] = whiA + wofs[l];
        wa.lo[l] = wloA + wofs[l];
        wa.cin[l] = CINS[l];
        wa.start[l] = wofs[l];
    }
    wa.start[7] = wofs[7];
    wtrans_all<<<(wofs[7] + 255) / 256, 256, 0, stream>>>(wa);

    // conv1 + conv2 over 4 chunks of 16 images
    for (int ch = 0; ch < 4; ch++) {
        conv1_kernel<<<dim3(64, 16), 256, 0, stream>>>(
            TI1 + (size_t)ch * 16 * 2 * 128 * 128, w[0], cbp[0], sp[0], tp[0], A);
        conv_mfma<64, 64, 128, 128, 2, 32><<<dim3(64, 1, 16), 512, 0, stream>>>(
            A, whiA + wofs[0], wloA + wofs[0], cbp[1], sp[1], tp[1],
            Bb + (size_t)ch * 16 * 64 * 64 * 64);
    }
    // conv3..conv8 full batch, ping-pong Bb <-> A
    conv_mfma<64, 64, 64, 64, 1, 32><<<dim3(16, 1, 64), 512, 0, stream>>>(
        Bb, whiA + wofs[1], wloA + wofs[1], cbp[2], sp[2], tp[2], A);
    conv_mfma<64, 64, 64, 64, 2, 32><<<dim3(16, 1, 64), 512, 0, stream>>>(
        A, whiA + wofs[2], wloA + wofs[2], cbp[3], sp[3], tp[3], Bb);
    conv_mfma<64, 128, 32, 32, 1, 32><<<dim3(4, 2, 64), 512, 0, stream>>>(
        Bb, whiA + wofs[3], wloA + wofs[3], cbp[4], sp[4], tp[4], A);
    conv_mfma<128, 128, 32, 32, 2, 32><<<dim3(4, 2, 64), 512, 0, stream>>>(
        A, whiA + wofs[4], wloA + wofs[4], cbp[5], sp[5], tp[5], Bb);
    conv_mfma<128, 128, 16, 16, 1, 16><<<dim3(1, 2, 64), 512, 0, stream>>>(
        Bb, whiA + wofs[5], wloA + wofs[5], cbp[6], sp[6], tp[6], A);
    conv_mfma<128, 128, 16, 16, 1, 16><<<dim3(1, 2, 64), 512, 0, stream>>>(
        A, whiA + wofs[6], wloA + wofs[6], cbp[7], sp[7], tp[7], Bb);

    pool6_kernel<<<128, 256, 0, stream>>>(Bb, feat);
    fc1_kernel<<<dim3(4, 64), 256, 0, stream>>>(feat, fcw, fcb, fc1o);
    fc2_kernel<<<64, 256, 0, stream>>>(fc1o, f1w, f1b, h4pt);
    dlt_kernel<<<1, 64, 0, stream>>>(h4pt, TCorner, hinv);
    warp_kernel<<<dim3(64, 64), 256, 0, stream>>>(TImgA, hinv, outp);
}

// Round 5
// 387.543 us; speedup vs baseline: 10.6636x; 1.1839x over previous
//
#include <hip/hip_runtime.h>
#include <math.h>

typedef __attribute__((ext_vector_type(4))) float f32x4;
typedef __attribute__((ext_vector_type(8))) short sh8;

__device__ __forceinline__ float bf2f(unsigned short u){
    union { unsigned int i; float f; } v; v.i = ((unsigned)u) << 16; return v.f;
}
__device__ __forceinline__ unsigned short f2bf(float f){
    union { float f; unsigned int i; } v; v.f = f;
    unsigned int x = v.i;
    x += 0x7fff + ((x >> 16) & 1);   // RNE; inputs finite
    return (unsigned short)(x >> 16);
}

// ---------------------------------------------------------------------------
// Merged weight transform conv2..conv8:
// w [COUT][CIN][3][3] fp32 -> wT [tap][COUT][CIN] bf16 (RNE)
// ---------------------------------------------------------------------------
struct WTArgs {
    const float* src[7];
    unsigned short* hi[7];
    int cin[7];
    int start[8];
};

__global__ void wtrans_all(WTArgs a)
{
    int e = blockIdx.x * 256 + threadIdx.x;
    if (e >= a.start[7]) return;
    int l = 0;
    while (e >= a.start[l + 1]) l++;
    int eL = e - a.start[l];
    int CIN = a.cin[l];
    int tap = eL % 9, rest = eL / 9;
    int ci = rest % CIN, co = rest / CIN;
    int COUT = (a.start[l + 1] - a.start[l]) / (9 * CIN);
    a.hi[l][(tap * COUT + co) * CIN + ci] = f2bf(a.src[l][eL]);
}

// ---------------------------------------------------------------------------
// conv1: Cin=2 fp32 direct conv + BN + ReLU -> NHWC bf16
// ---------------------------------------------------------------------------
__global__ __launch_bounds__(256) void conv1_kernel(
    const float* __restrict__ in, const float* __restrict__ w,
    const float* __restrict__ cb, const float* __restrict__ sc,
    const float* __restrict__ tb, unsigned short* __restrict__ out)
{
    __shared__ float s_w[18 * 64];
    __shared__ float s_in[2][18 * 20];

    const int tid = threadIdx.x;
    const int b = blockIdx.y;
    const int tile = blockIdx.x;
    const int ty = tile >> 3, tx = tile & 7;
    const int y0 = ty * 16, x0 = tx * 16;

    for (int idx = tid; idx < 1152; idx += 256) {
        int co = idx & 63, kk2 = idx >> 6;
        s_w[kk2 * 64 + co] = w[co * 18 + kk2];
    }
    for (int idx = tid; idx < 2 * 324; idx += 256) {
        int ci = idx / 324, rem = idx % 324;
        int r = rem / 18, c = rem % 18;
        int gy = y0 + r - 1, gx = x0 + c - 1;
        float v = 0.f;
        if (gy >= 0 && gy < 128 && gx >= 0 && gx < 128)
            v = in[((size_t)(b * 2 + ci) * 128 + gy) * 128 + gx];
        s_in[ci][r * 20 + c] = v;
    }
    __syncthreads();

    const int cog = tid >> 5;
    const int slot = tid & 31;
    const int sy = slot >> 2, sx = slot & 3;

    float p[2][4][6];
#pragma unroll
    for (int ci = 0; ci < 2; ci++)
#pragma unroll
        for (int r = 0; r < 4; r++)
#pragma unroll
            for (int c = 0; c < 6; c++)
                p[ci][r][c] = s_in[ci][(2 * sy + r) * 20 + 4 * sx + c];

    float acc[2][4][8];
#pragma unroll
    for (int r = 0; r < 2; r++)
#pragma unroll
        for (int c = 0; c < 4; c++)
#pragma unroll
            for (int o = 0; o < 8; o++) acc[r][c][o] = 0.f;

#pragma unroll
    for (int kk2 = 0; kk2 < 18; kk2++) {
        const int ci = kk2 / 9, k = kk2 % 9;
        const int ky = k / 3, kx = k % 3;
        float wv[8];
#pragma unroll
        for (int q = 0; q < 2; q++) {
            f32x4 w4 = *(const f32x4*)(&s_w[kk2 * 64 + cog * 8 + q * 4]);
#pragma unroll
            for (int z = 0; z < 4; z++) wv[q * 4 + z] = w4[z];
        }
#pragma unroll
        for (int r = 0; r < 2; r++)
#pragma unroll
            for (int c = 0; c < 4; c++) {
                float pv = p[ci][r + ky][c + kx];
#pragma unroll
                for (int o = 0; o < 8; o++) acc[r][c][o] += pv * wv[o];
            }
    }

    float bb[8], ss[8], tt[8];
#pragma unroll
    for (int o = 0; o < 8; o++) { bb[o] = cb[cog*8+o]; ss[o] = sc[cog*8+o]; tt[o] = tb[cog*8+o]; }
#pragma unroll
    for (int r = 0; r < 2; r++)
#pragma unroll
        for (int c = 0; c < 4; c++) {
            unsigned short ov[8];
#pragma unroll
            for (int o = 0; o < 8; o++)
                ov[o] = f2bf(fmaxf((acc[r][c][o] + bb[o]) * ss[o] + tt[o], 0.f));
            int py = y0 + 2 * sy + r, px = x0 + 4 * sx + c;
            *(sh8*)(out + ((size_t)(b * 128 + py) * 128 + px) * 64 + cog * 8) = *(sh8*)ov;
        }
}

// ---------------------------------------------------------------------------
// MFMA implicit-GEMM conv3x3 + BN + ReLU (+ fused 2x2 maxpool), v4:
// 4 waves (256 thr); tile 256 px x 64 cout; each wave owns 64 px x 64 cout
// (acc 4x4 f32x4 = 64 VGPR) -> A-frags read once per tap (no replication),
// B replication x4. Single-bf16 weights (no hi/lo). Barrier per TAP:
// tap-granular weight double-buffer in LDS (2 x 8KB), global->reg prefetch
// issued before the 32-MFMA burst, ds_write after (latency hidden).
// LDS bank hygiene: A pixel stride 136B (uniform minimal banking);
// weight row [co][64ci] with granule rotation slot = g ^ (co&7) baked into
// the physical layout on BOTH write and read (uniform 8/bank).
// ---------------------------------------------------------------------------
template<int CIN, int COUT, int HI, int WI, int POOL, int TW>
__global__ __launch_bounds__(256, 2) void conv_mfma(
    const unsigned short* __restrict__ in,
    const unsigned short* __restrict__ whi,
    const float* __restrict__ cb, const float* __restrict__ sc,
    const float* __restrict__ tb, unsigned short* __restrict__ out)
{
    constexpr int TH = 256 / TW;
    constexpr int HALW = TW + 2, HALH = TH + 2;
    constexpr int NPIX = HALW * HALH;
    constexpr int CHUNKS = CIN / 64;
    constexpr int TILESX = WI / TW;
    constexpr int HO = HI / POOL, WO = WI / POOL;
    constexpr int ST = 68;               // ushorts per pixel (136B)

    __shared__ __align__(16) unsigned short lds_A[NPIX * ST];
    __shared__ __align__(16) unsigned short lds_W[2][4096];   // [buf][co*64 + slot*8]

    const int tid = threadIdx.x;
    const int lane = tid & 63;
    const int i = lane & 15, j = lane >> 4;
    const int wv = tid >> 6;             // 0..3
    const int tile = blockIdx.x;
    const int ty = tile / TILESX, tx = tile % TILESX;
    const int y0 = ty * TH, x0 = tx * TW;
    const int coBase = blockIdx.y * 64;
    const int b = blockIdx.z;

    // weight-staging role: 256 threads x 32B (two 16B granules at phys slots gp, gp+4)
    const int co_s = tid >> 2;           // 0..63
    const int gp = tid & 3;

    f32x4 acc[4][4];
#pragma unroll
    for (int pf = 0; pf < 4; pf++)
#pragma unroll
        for (int cf = 0; cf < 4; cf++) acc[pf][cf] = (f32x4){0.f, 0.f, 0.f, 0.f};

    sh8 rw[2];

    for (int c = 0; c < CHUNKS; c++) {
        if (c) __syncthreads();          // all reads of prev chunk's LDS done

        // ---- stage A halo: NPIX pixels x 64 cin, zero-padded ----
        for (int u = tid; u < NPIX * 8; u += 256) {
            int hp = u >> 3, c16 = u & 7;
            int hy = hp / HALW, hx = hp % HALW;
            int gy = y0 + hy - 1, gx = x0 + hx - 1;
            sh8 v = (sh8){0,0,0,0,0,0,0,0};
            if (gy >= 0 && gy < HI && gx >= 0 && gx < WI)
                v = *(const sh8*)(in + ((size_t)(b * HI + gy) * WI + gx) * CIN + c * 64 + c16 * 8);
            *(sh8*)(&lds_A[hp * ST + c16 * 8]) = v;
        }

        const unsigned short* wrow = whi + ((size_t)(coBase + co_s)) * CIN + c * 64;

        auto LOADW = [&](int tap) {
#pragma unroll
            for (int q = 0; q < 2; q++) {
                int pp = gp + q * 4;                 // physical slot
                int gl = pp ^ (co_s & 7);            // logical granule stored there
                rw[q] = *(const sh8*)(wrow + (size_t)tap * COUT * CIN + gl * 8);
            }
        };
        auto WRITEW = [&](int bi) {
#pragma unroll
            for (int q = 0; q < 2; q++) {
                int pp = gp + q * 4;
                *(sh8*)(&lds_W[bi][co_s * 64 + pp * 8]) = rw[q];
            }
        };

        LOADW(0); WRITEW(0);
        __syncthreads();

#pragma unroll
        for (int tap = 0; tap < 9; tap++) {
            if (tap < 8) LOADW(tap + 1);             // global prefetch (covered by MFMA burst)
            const int ky = tap / 3, kx = tap % 3;
            const int bi = tap & 1;
            sh8 aF[8], bF[8];
#pragma unroll
            for (int kk = 0; kk < 2; kk++) {
#pragma unroll
                for (int pf = 0; pf < 4; pf++) {
                    const int nf = wv * 4 + pf;
                    int hy2, hx2;
                    if (TW == 32) { hy2 = (nf >> 1) + ky; hx2 = (nf & 1) * 16 + i + kx; }
                    else          { hy2 = nf + ky;        hx2 = i + kx; }
                    aF[kk * 4 + pf] = *(const sh8*)(&lds_A[(hy2 * HALW + hx2) * ST + kk * 32 + j * 8]);
                }
#pragma unroll
                for (int cf = 0; cf < 4; cf++) {
                    const int co_l = cf * 16 + i;
                    bF[kk * 4 + cf] = *(const sh8*)(&lds_W[bi][co_l * 64
                        + ((((kk << 2) | j) ^ (i & 7)) * 8)]);
                }
            }
            __builtin_amdgcn_s_setprio(1);
#pragma unroll
            for (int kk = 0; kk < 2; kk++)
#pragma unroll
                for (int pf = 0; pf < 4; pf++)
#pragma unroll
                    for (int cf = 0; cf < 4; cf++)
                        acc[pf][cf] = __builtin_amdgcn_mfma_f32_16x16x32_bf16(
                            aF[kk * 4 + pf], bF[kk * 4 + cf], acc[pf][cf], 0, 0, 0);
            __builtin_amdgcn_s_setprio(0);
            if (tap < 8) { WRITEW((tap + 1) & 1); __syncthreads(); }
        }
    }

    // ---- epilogue: BN + ReLU (+pool); D: col(i)=cout, row(j*4+r)=pixel ----
#pragma unroll
    for (int cf = 0; cf < 4; cf++) {
        const int co = coBase + cf * 16 + i;
        const float b3 = cb[co], s3 = sc[co], t3 = tb[co];
        if (POOL == 1) {
#pragma unroll
            for (int pf = 0; pf < 4; pf++) {
                const int nf = wv * 4 + pf;
                int py, pxb;
                if (TW == 32) { py = nf >> 1; pxb = (nf & 1) * 16; }
                else          { py = nf;      pxb = 0; }
#pragma unroll
                for (int r = 0; r < 4; r++) {
                    float v = fmaxf((acc[pf][cf][r] + b3) * s3 + t3, 0.f);
                    int px = pxb + j * 4 + r;
                    out[((size_t)(b * HO + y0 + py) * WO + x0 + px) * COUT + co] = f2bf(v);
                }
            }
        } else if constexpr (POOL == 2 && TW == 32) {
            // wave rows 2wv,2wv+1 -> pooled row wv
#pragma unroll
            for (int h = 0; h < 2; h++) {
                const int pfA = h, pfB = 2 + h;
#pragma unroll
                for (int r2 = 0; r2 < 2; r2++) {
                    float vA0 = fmaxf((acc[pfA][cf][2*r2]   + b3) * s3 + t3, 0.f);
                    float vA1 = fmaxf((acc[pfA][cf][2*r2+1] + b3) * s3 + t3, 0.f);
                    float vB0 = fmaxf((acc[pfB][cf][2*r2]   + b3) * s3 + t3, 0.f);
                    float vB1 = fmaxf((acc[pfB][cf][2*r2+1] + b3) * s3 + t3, 0.f);
                    float v = fmaxf(fmaxf(vA0, vA1), fmaxf(vB0, vB1));
                    int pox = (x0 >> 1) + h * 8 + j * 2 + r2;
                    int poy = (y0 >> 1) + wv;
                    out[((size_t)(b * HO + poy) * WO + pox) * COUT + co] = f2bf(v);
                }
            }
        }
    }
}

// ---------------------------------------------------------------------------
// 6x6/6 maxpool on NHWC bf16 (64,16,16,128) -> feat fp32 [b][c*4+oy*2+ox]
// ---------------------------------------------------------------------------
__global__ void pool6_kernel(const unsigned short* __restrict__ in, float* __restrict__ out)
{
    int t = blockIdx.x * 256 + threadIdx.x;
    if (t >= 64 * 128 * 4) return;
    int ox = t & 1, oy = (t >> 1) & 1, c = (t >> 2) & 127, b = t >> 9;
    const unsigned short* p = in + ((size_t)(b * 16 + oy * 6) * 16 + ox * 6) * 128 + c;
    float m = -INFINITY;
#pragma unroll
    for (int r = 0; r < 6; r++)
#pragma unroll
        for (int cc = 0; cc < 6; cc++) m = fmaxf(m, bf2f(p[(r * 16 + cc) * 128]));
    out[(size_t)b * 512 + c * 4 + oy * 2 + ox] = m;
}

// ---------------------------------------------------------------------------
// FC1 / FC2 / DLT / warp
// ---------------------------------------------------------------------------
__global__ void fc1_kernel(const float* __restrict__ flat, const float* __restrict__ fcw,
                           const float* __restrict__ fcb, float* __restrict__ out1)
{
    int b = blockIdx.y;
    int jj = blockIdx.x * 256 + threadIdx.x;
    const f32x4* f = (const f32x4*)(flat + (size_t)b * 512);
    const f32x4* w = (const f32x4*)(fcw + (size_t)jj * 512);
    float s = fcb[jj];
    for (int k = 0; k < 128; k++) {
        f32x4 a = f[k], ww = w[k];
        s += a[0]*ww[0] + a[1]*ww[1] + a[2]*ww[2] + a[3]*ww[3];
    }
    out1[(size_t)b * 1024 + jj] = fmaxf(s, 0.f);
}

__global__ void fc2_kernel(const float* __restrict__ out1, const float* __restrict__ f1w,
                           const float* __restrict__ f1b, float* __restrict__ h4pt)
{
    int b = blockIdx.x;
    int o = threadIdx.x >> 5, s2 = threadIdx.x & 31;
    const float* pa = out1 + (size_t)b * 1024;
    const float* pw = f1w + (size_t)o * 1024;
    float s = 0.f;
    for (int k = s2; k < 1024; k += 32) s += pa[k] * pw[k];
#pragma unroll
    for (int m = 16; m; m >>= 1) s += __shfl_xor(s, m);
    if (s2 == 0) h4pt[b * 8 + o] = s + f1b[o];
}

__global__ void dlt_kernel(const float* __restrict__ h4pt, const float* __restrict__ corner,
                           double* __restrict__ hinv)
{
    int b = threadIdx.x;
    if (b >= 64) return;
    double U[4], V[4], Ud[4], Vd[4];
    for (int jq = 0; jq < 4; jq++) {
        U[jq] = (double)corner[b * 8 + 2 * jq];
        V[jq] = (double)corner[b * 8 + 2 * jq + 1];
        Ud[jq] = U[jq] + (double)h4pt[b * 8 + 2 * jq];
        Vd[jq] = V[jq] + (double)h4pt[b * 8 + 2 * jq + 1];
    }
    double A[8][9];
    for (int jq = 0; jq < 4; jq++) {
        double* r0 = A[2 * jq];
        double* r1 = A[2 * jq + 1];
        r0[0] = 0;     r0[1] = 0;     r0[2] = 0;
        r0[3] = -U[jq]; r0[4] = V[jq]; r0[5] = -1;
        r0[6] = Vd[jq] * U[jq]; r0[7] = Vd[jq] * V[jq]; r0[8] = -Vd[jq];
        r1[0] = U[jq]; r1[1] = V[jq]; r1[2] = 1;
        r1[3] = 0;     r1[4] = 0;     r1[5] = 0;
        r1[6] = -Ud[jq] * U[jq]; r1[7] = -Ud[jq] * V[jq]; r1[8] = Ud[jq];
    }
    for (int col = 0; col < 8; col++) {
        int piv = col; double mx = fabs(A[col][col]);
        for (int r = col + 1; r < 8; r++) {
            double v = fabs(A[r][col]);
            if (v > mx) { mx = v; piv = r; }
        }
        if (piv != col)
            for (int cc = col; cc < 9; cc++) { double tmp = A[col][cc]; A[col][cc] = A[piv][cc]; A[piv][cc] = tmp; }
        double inv = 1.0 / A[col][col];
        for (int r = col + 1; r < 8; r++) {
            double f = A[r][col] * inv;
            for (int cc = col; cc < 9; cc++) A[r][cc] -= f * A[col][cc];
        }
    }
    double h[9];
    for (int r = 7; r >= 0; r--) {
        double s = A[r][8];
        for (int cc = r + 1; cc < 8; cc++) s -= A[r][cc] * h[cc];
        h[r] = s / A[r][r];
    }
    h[8] = 1.0;
    double a = h[0], bb = h[1], cq = h[2], d = h[3], e = h[4], f = h[5], g = h[6], hh = h[7], iq = h[8];
    double C00 = e * iq - f * hh, C01 = cq * hh - bb * iq, C02 = bb * f - cq * e;
    double C10 = f * g - d * iq,  C11 = a * iq - cq * g,   C12 = cq * d - a * f;
    double C20 = d * hh - e * g,  C21 = bb * g - a * hh,   C22 = a * e - bb * d;
    double det = a * C00 + bb * C10 + cq * C20;
    double idet = 1.0 / det;
    double* o = hinv + b * 9;
    o[0] = C00 * idet; o[1] = C01 * idet; o[2] = C02 * idet;
    o[3] = C10 * idet; o[4] = C11 * idet; o[5] = C12 * idet;
    o[6] = C20 * idet; o[7] = C21 * idet; o[8] = C22 * idet;
}

__global__ void warp_kernel(const float* __restrict__ img, const double* __restrict__ hinv,
                            float* __restrict__ out)
{
    int b = blockIdx.y;
    int pix = blockIdx.x * 256 + threadIdx.x;
    int y = pix >> 7, x = pix & 127;
    const double* h = hinv + b * 9;
    double X = (double)x, Y = (double)y;
    double p0 = h[0] * X + h[1] * Y + h[2];
    double p1 = h[3] * X + h[4] * Y + h[5];
    double p2 = h[6] * X + h[7] * Y + h[8];
    double xs = p0 / p2, ys = p1 / p2;
    double x0d = floor(xs), y0d = floor(ys);
    double wx = xs - x0d, wy = ys - y0d;
    int x0 = (int)x0d, y0 = (int)y0d;
    const float* im = img + (size_t)b * 240 * 320;
    auto gat = [&](int yi, int xi) -> double {
        bool valid = (xi >= 0) & (xi < 320) & (yi >= 0) & (yi < 240);
        int yc = yi < 0 ? 0 : (yi > 239 ? 239 : yi);
        int xc = xi < 0 ? 0 : (xi > 319 ? 319 : xi);
        double v = (double)im[yc * 320 + xc];
        return valid ? v : 0.0;
    };
    double v00 = gat(y0, x0),     v01 = gat(y0, x0 + 1);
    double v10 = gat(y0 + 1, x0), v11 = gat(y0 + 1, x0 + 1);
    double r = v00 * (1 - wx) * (1 - wy) + v01 * wx * (1 - wy)
             + v10 * (1 - wx) * wy       + v11 * wx * wy;
    out[((size_t)b << 14) + pix] = (float)r;
}

// ---------------------------------------------------------------------------
// launch — ping-pong A<->Bb (2x 33.5 MB), ~69 MB workspace
// ---------------------------------------------------------------------------
extern "C" void kernel_launch(void* const* d_in, const int* in_sizes, int n_in,
                              void* d_out, int out_size, void* d_ws, size_t ws_size,
                              hipStream_t stream)
{
    const float* TI1     = (const float*)d_in[1];
    const float* TImgA   = (const float*)d_in[2];
    const float* TCorner = (const float*)d_in[3];
    const float* w[8], *cbp[8], *sp[8], *tp[8];
    for (int l = 0; l < 8; l++) {
        w[l]   = (const float*)d_in[4 + 4 * l];
        cbp[l] = (const float*)d_in[5 + 4 * l];
        sp[l]  = (const float*)d_in[6 + 4 * l];
        tp[l]  = (const float*)d_in[7 + 4 * l];
    }
    const float* fcw = (const float*)d_in[36];
    const float* fcb = (const float*)d_in[37];
    const float* f1w = (const float*)d_in[38];
    const float* f1b = (const float*)d_in[39];

    char* base = (char*)d_ws;
    unsigned short* A    = (unsigned short*)(base);
    unsigned short* Bb   = (unsigned short*)(base + 33554432);
    unsigned short* whiA = (unsigned short*)(base + 67108864);   // 1,253,376 B
    float*  feat = (float*) (base + 67108864 + 1253376);
    float*  fc1o = feat + 64 * 512;
    float*  h4pt = fc1o + 64 * 1024;
    double* hinv = (double*)(h4pt + 512);
    float*  outp = (float*)d_out;

    const int CINS[7]  = {64, 64, 64, 64, 128, 128, 128};
    const int COUTS[7] = {64, 64, 64, 128, 128, 128, 128};
    int wofs[8]; wofs[0] = 0;
    for (int l = 0; l < 7; l++) wofs[l + 1] = wofs[l] + 9 * COUTS[l] * CINS[l];

    WTArgs wa;
    for (int l = 0; l < 7; l++) {
        wa.src[l] = w[l + 1];
        wa.hi[l] = whiA + wofs[l];
        wa.cin[l] = CINS[l];
        wa.start[l] = wofs[l];
    }
    wa.start[7] = wofs[7];
    wtrans_all<<<(wofs[7] + 255) / 256, 256, 0, stream>>>(wa);

    // conv1 + conv2 over 4 chunks of 16 images
    for (int ch = 0; ch < 4; ch++) {
        conv1_kernel<<<dim3(64, 16), 256, 0, stream>>>(
            TI1 + (size_t)ch * 16 * 2 * 128 * 128, w[0], cbp[0], sp[0], tp[0], A);
        conv_mfma<64, 64, 128, 128, 2, 32><<<dim3(64, 1, 16), 256, 0, stream>>>(
            A, whiA + wofs[0], cbp[1], sp[1], tp[1],
            Bb + (size_t)ch * 16 * 64 * 64 * 64);
    }
    // conv3..conv8 full batch, ping-pong Bb <-> A
    conv_mfma<64, 64, 64, 64, 1, 32><<<dim3(16, 1, 64), 256, 0, stream>>>(
        Bb, whiA + wofs[1], cbp[2], sp[2], tp[2], A);
    conv_mfma<64, 64, 64, 64, 2, 32><<<dim3(16, 1, 64), 256, 0, stream>>>(
        A, whiA + wofs[2], cbp[3], sp[3], tp[3], Bb);
    conv_mfma<64, 128, 32, 32, 1, 32><<<dim3(4, 2, 64), 256, 0, stream>>>(
        Bb, whiA + wofs[3], cbp[4], sp[4], tp[4], A);
    conv_mfma<128, 128, 32, 32, 2, 32><<<dim3(4, 2, 64), 256, 0, stream>>>(
        A, whiA + wofs[4], cbp[5], sp[5], tp[5], Bb);
    conv_mfma<128, 128, 16, 16, 1, 16><<<dim3(1, 2, 64), 256, 0, stream>>>(
        Bb, whiA + wofs[5], cbp[6], sp[6], tp[6], A);
    conv_mfma<128, 128, 16, 16, 1, 16><<<dim3(1, 2, 64), 256, 0, stream>>>(
        A, whiA + wofs[6], cbp[7], sp[7], tp[7], Bb);

    pool6_kernel<<<128, 256, 0, stream>>>(Bb, feat);
    fc1_kernel<<<dim3(4, 64), 256, 0, stream>>>(feat, fcw, fcb, fc1o);
    fc2_kernel<<<64, 256, 0, stream>>>(fc1o, f1w, f1b, h4pt);
    dlt_kernel<<<1, 64, 0, stream>>>(h4pt, TCorner, hinv);
    warp_kernel<<<dim3(64, 64), 256, 0, stream>>>(TImgA, hinv, outp);
}